// Round 7
// baseline (394.219 us; speedup 1.0000x reference)
//
#include <hip/hip_runtime.h>
#include <math.h>

#define B_ 256
#define L_ 100
#define H_ 8

// Output offsets (floats): V[B,L,H,64], series[B,H,L,L], prior, sig, M[B,H,L]
#define OFF_SERIES ((size_t)B_ * L_ * H_ * 64)
#define OFF_PRIOR  (OFF_SERIES + (size_t)B_ * H_ * L_ * L_)
#define OFF_SIG    (OFF_PRIOR  + (size_t)B_ * H_ * L_ * L_)
#define OFF_M      (OFF_SIG    + (size_t)B_ * H_ * L_ * L_)

#define LOG2E 1.4426950408889634f
#define LN3   1.0986122886681098f
#define INV_SQRT_2PI 0.3989422804014327f

typedef __attribute__((ext_vector_type(8))) short short8b;  // 8 bf16
typedef __attribute__((ext_vector_type(4))) float f32x4;

// LDS layout (bytes)
#define KHI 0          // K hi bf16 [100][64], 128B rows, XOR-swizzled: 12800
#define KLO 12800      // K lo bf16: 12800
#define PR  25600      // P bf16, 4 waves x [16 rows][104 cols] (208B rows): 13312
#define VT  38912      // V^T bf16 [64 d][104 j] (208B rows, no swizzle): 13312
#define DEN 52224      // 64 f32
#define SMEM_BYTES 52480   // -> 3 blocks/CU

__device__ __forceinline__ void cvt_split8(const float* f, short8b& hi, short8b& lo) {
#pragma unroll
    for (int i = 0; i < 8; ++i) {
        unsigned u = __float_as_uint(f[i]);
        hi[i] = (short)(u >> 16);
        float r = f[i] - __uint_as_float(u & 0xFFFF0000u);
        lo[i] = (short)(__float_as_uint(r) >> 16);
    }
}
__device__ __forceinline__ unsigned short f2bf_rn(float x) {  // round-to-nearest-even
    unsigned u = __float_as_uint(x);
    return (unsigned short)((u + 0x7FFFu + ((u >> 16) & 1u)) >> 16);
}
__device__ __forceinline__ float bf2f(unsigned short v) {
    return __uint_as_float((unsigned)v << 16);
}

__global__ __launch_bounds__(256) void fused_kernel(
    const float* __restrict__ Q, const float* __restrict__ K,
    const float* __restrict__ Vin, const float* __restrict__ sigma,
    const float* __restrict__ dist, float* __restrict__ Vout,
    float* __restrict__ series, float* __restrict__ prior,
    float* __restrict__ sigout, float* __restrict__ Mout) {
    const int bid = blockIdx.x;
    const int b = bid >> 3, h = bid & 7;
    __shared__ __align__(16) char smem[SMEM_BYTES];
    float* den_s = (float*)(smem + DEN);
    const int t = threadIdx.x;
    const int wave = t >> 6;
    const int lane = t & 63;
    const int lr = lane & 15;   // MFMA col (= l offset) / A-row offset
    const int g  = lane >> 4;   // k-group
    const int nt = (wave < 3) ? 2 : 1;   // tiles per wave (7 l-tiles of 16)

    // ---- Q B-frags: per-lane GLOBAL loads (VMEM) + register split-bf16 ----
    short8b qh[2][2], ql[2][2];
    for (int ti = 0; ti < nt; ++ti) {
        int lrow = (wave * 2 + ti) * 16 + lr; if (lrow > 99) lrow = 99;
        const float* qp = Q + ((size_t)(b * L_ + lrow) * H_ + h) * 64;
#pragma unroll
        for (int es = 0; es < 2; ++es) {
            float4 f0 = *(const float4*)(qp + es * 32 + g * 8);
            float4 f1 = *(const float4*)(qp + es * 32 + g * 8 + 4);
            float f[8] = {f0.x, f0.y, f0.z, f0.w, f1.x, f1.y, f1.z, f1.w};
            cvt_split8(f, qh[ti][es], ql[ti][es]);
        }
    }

    // ---- stage K as split-bf16 hi/lo (row XOR-swizzle, R4-proven) ----
    for (int ci = t; ci < 800; ci += 256) {
        int row = ci >> 3, c8 = ci & 7;
        const float* src = K + ((size_t)(b * L_ + row) * H_ + h) * 64 + c8 * 8;
        float4 f0 = *(const float4*)src;
        float4 f1 = *(const float4*)(src + 4);
        float f[8] = {f0.x, f0.y, f0.z, f0.w, f1.x, f1.y, f1.z, f1.w};
        short8b hi8, lo8;
        cvt_split8(f, hi8, lo8);
        int byte = (row * 128 + c8 * 16) ^ ((row & 7) << 4);
        *(short8b*)(smem + KHI + byte) = hi8;
        *(short8b*)(smem + KLO + byte) = lo8;
    }
    // ---- stage V^T as bf16 (rounded), [64][104], plain 208B rows ----
    for (int f = t; f < 1600; f += 256) {
        int j = f >> 4, c = f & 15;
        float4 v = *(const float4*)(Vin + ((size_t)(b * L_ + j) * H_ + h) * 64 + c * 4);
        float vv[4] = {v.x, v.y, v.z, v.w};
#pragma unroll
        for (int i = 0; i < 4; ++i) {
            int d = c * 4 + i;
            *(unsigned short*)(smem + VT + d * 208 + j * 2) = f2bf_rn(vv[i]);
        }
    }
    if (t < 64) {  // zero V^T cols 100..103 (k-tail)
        uint2 z; z.x = 0; z.y = 0;
        *(uint2*)(smem + VT + t * 208 + 200) = z;
    }
    __syncthreads();

    const float cs = 0.125f * LOG2E;
    const size_t bh = (size_t)(b * H_ + h);
    char* pbase = smem + PR + wave * 3328;   // [16][104] bf16 per wave

    for (int ti = 0; ti < nt; ++ti) {
        const int lt = wave * 2 + ti;
        const int l = lt * 16 + lr;      // this lane's output row (may be >=100)

        // ======== Phase C: scores via split-bf16 MFMA, stats, series, M ====
        float m1 = -INFINITY, m2 = -INFINITY, sum1 = 0.f, sum2 = 0.f, den = 0.f;
        for (int jt = 0; jt < 7; ++jt) {
            int jrow = jt * 16 + lr; if (jrow > 99) jrow = 99;
            int rb = jrow * 128, sw = (jrow & 7) << 4;
            f32x4 C = {0.f, 0.f, 0.f, 0.f};
#pragma unroll
            for (int es = 0; es < 2; ++es) {
                int byte = (rb + g * 16 + es * 64) ^ sw;
                short8b kh = *(const short8b*)(smem + KHI + byte);
                short8b kl = *(const short8b*)(smem + KLO + byte);
                C = __builtin_amdgcn_mfma_f32_16x16x32_bf16(kh, qh[ti][es], C, 0, 0, 0);
                C = __builtin_amdgcn_mfma_f32_16x16x32_bf16(kh, ql[ti][es], C, 0, 0, 0);
                C = __builtin_amdgcn_mfma_f32_16x16x32_bf16(kl, qh[ti][es], C, 0, 0, 0);
            }
            unsigned short pw[4] = {0, 0, 0, 0};
#pragma unroll
            for (int r = 0; r < 4; ++r) {
                int j = jt * 16 + g * 4 + r;
                float s = C[r];
                if (j < 100) {
                    m1 = fmaxf(m1, s);
                    sum1 += s;
                    bool band = (j - l < 3) && (l - j < 3);
                    float sp = band ? 0.f : s;
                    m2 = fmaxf(m2, sp);
                    sum2 += sp;
                    float p = exp2f(s * cs);
                    den += p;                             // diag included in den
                    pw[r] = (j == l) ? 0 : f2bf_rn(p);    // diag zeroed in P
                }
            }
            if (jt < 6 || g < 2) {   // cols 0..99 real, 100..103 zero pad
                uint2 pk;
                pk.x = (unsigned)pw[0] | ((unsigned)pw[1] << 16);
                pk.y = (unsigned)pw[2] | ((unsigned)pw[3] << 16);
                *(uint2*)(pbase + lr * 208 + jt * 32 + g * 8) = pk;
            }
        }
        m1   = fmaxf(m1, __shfl_xor(m1, 16, 64));
        m1   = fmaxf(m1, __shfl_xor(m1, 32, 64));
        m2   = fmaxf(m2, __shfl_xor(m2, 16, 64));
        m2   = fmaxf(m2, __shfl_xor(m2, 32, 64));
        sum1 += __shfl_xor(sum1, 16, 64);
        sum1 += __shfl_xor(sum1, 32, 64);
        sum2 += __shfl_xor(sum2, 16, 64);
        sum2 += __shfl_xor(sum2, 32, 64);
        den  += __shfl_xor(den, 16, 64);
        den  += __shfl_xor(den, 32, 64);
        const float invd_own = 1.0f / den;   // valid where l < 100
        if (lane < 16 && l < 100) {
            den_s[wave * 16 + lr] = den;
            float M1 = m1 - sum1 * (1.0f / 100.0f);
            float M2 = m2 - sum2 * (1.0f / 94.0f);
            Mout[bh * L_ + l] = M1 - M2;
        }
        // normalize + coalesced series copy-out (bf16 P -> f32)
        for (int f = lane; f < 400; f += 64) {
            int row = f / 25, c = f - row * 25;
            int lg = lt * 16 + row;
            if (lg < 100) {
                uint2 pk = *(const uint2*)(pbase + row * 208 + c * 8);
                float invd = 1.0f / den_s[wave * 16 + row];
                f32x4 p;
                p.x = bf2f((unsigned short)(pk.x & 0xFFFF)) * invd;
                p.y = bf2f((unsigned short)(pk.x >> 16))   * invd;
                p.z = bf2f((unsigned short)(pk.y & 0xFFFF)) * invd;
                p.w = bf2f((unsigned short)(pk.y >> 16))   * invd;
                *(f32x4*)(series + (bh * L_ + lg) * L_ + c * 4) = p;
            }
        }

        // ======== Phase D: (PV)^T = V^T . P^T — direct bf16 MFMA ========
        // k-tail: jt32==3 covers j=96..127; only g==0 slice (j 96..103) is
        // real (cols 100..103 zeroed). g>0 lanes: clamp LDS addr in-row and
        // ZERO the B-frag -> those k-slices contribute exactly 0.
        {
            f32x4 acc[4] = {{0.f,0.f,0.f,0.f},{0.f,0.f,0.f,0.f},
                            {0.f,0.f,0.f,0.f},{0.f,0.f,0.f,0.f}};
#pragma unroll
            for (int jt32 = 0; jt32 < 4; ++jt32) {
                const bool tail = (jt32 == 3) && (g > 0);
                const int off = tail ? (3 * 64) : (jt32 * 64 + g * 16);  // in-row
                short8b Bp = *(const short8b*)(pbase + lr * 208 + off);
                if (tail) {
                    short8b z = {0, 0, 0, 0, 0, 0, 0, 0};
                    Bp = z;
                }
#pragma unroll
                for (int dt = 0; dt < 4; ++dt) {
                    int d = dt * 16 + lr;
                    short8b Av = *(const short8b*)(smem + VT + d * 208 + off);
                    acc[dt] = __builtin_amdgcn_mfma_f32_16x16x32_bf16(Av, Bp, acc[dt], 0, 0, 0);
                }
            }
            if (l < 100) {
#pragma unroll
                for (int dt = 0; dt < 4; ++dt) {
                    f32x4 o = acc[dt];
                    o.x *= invd_own; o.y *= invd_own; o.z *= invd_own; o.w *= invd_own;
                    // lane holds out[l][dt*16 + g*4 .. +3]
                    *(f32x4*)(Vout + ((size_t)(b * L_ + l) * H_ + h) * 64 + dt * 16 + g * 4) = o;
                }
            }
        }
    }

    // ======== Phase E: prior + sig (independent, write-bound) ========
    {
        const size_t base4 = (size_t)(b * H_ + h) * 2500;
        const float4* d4 = (const float4*)dist;
        float4* p4 = (float4*)prior;
        float4* s4 = (float4*)sigout;
        for (int idx = t; idx < 2500; idx += 256) {
            int l = idx / 25;
            float x = sigma[((size_t)b * L_ + l) * H_ + h];
            float s = 1.0f / (1.0f + exp2f(-5.0f * LOG2E * x)) + 1e-5f;
            float sg = expm1f(s * LN3);   // 3^s - 1, accurate near 0
            float inv = 1.0f / sg;
            float c1 = INV_SQRT_2PI * inv;
            float c2 = 0.5f * LOG2E * inv * inv;
            float4 d = d4[idx];
            float4 pr;
            pr.x = c1 * exp2f(-d.x * d.x * c2);
            pr.y = c1 * exp2f(-d.y * d.y * c2);
            pr.z = c1 * exp2f(-d.z * d.z * c2);
            pr.w = c1 * exp2f(-d.w * d.w * c2);
            p4[base4 + idx] = pr;
            s4[base4 + idx] = make_float4(sg, sg, sg, sg);
        }
    }
}

extern "C" void kernel_launch(void* const* d_in, const int* in_sizes, int n_in,
                              void* d_out, int out_size, void* d_ws, size_t ws_size,
                              hipStream_t stream) {
    const float* Q     = (const float*)d_in[0];
    const float* K     = (const float*)d_in[1];
    const float* V     = (const float*)d_in[2];
    const float* sigma = (const float*)d_in[3];
    const float* dist  = (const float*)d_in[4];

    float* out    = (float*)d_out;
    float* Vout   = out;
    float* series = out + OFF_SERIES;
    float* prior  = out + OFF_PRIOR;
    float* sigout = out + OFF_SIG;
    float* Mout   = out + OFF_M;

    hipLaunchKernelGGL(fused_kernel, dim3(B_ * H_), dim3(256), 0, stream,
                       Q, K, V, sigma, dist, Vout, series, prior, sigout, Mout);
}

// Round 8
// 204.288 us; speedup vs baseline: 1.9297x; 1.9297x over previous
//
#include <hip/hip_runtime.h>
#include <math.h>

#define B_ 256
#define L_ 100
#define H_ 8
#define E_ 64
#define D_ 64

// Output offsets (floats): V[B,L,H,D], series[B,H,L,L], prior, sig, M[B,H,L]
#define OFF_SERIES ((size_t)B_ * L_ * H_ * D_)
#define OFF_PRIOR  (OFF_SERIES + (size_t)B_ * H_ * L_ * L_)
#define OFF_SIG    (OFF_PRIOR  + (size_t)B_ * H_ * L_ * L_)
#define OFF_M      (OFF_SIG    + (size_t)B_ * H_ * L_ * L_)

#define LOG2E 1.4426950408889634f
#define LN3   1.0986122886681098f
#define INV_SQRT_2PI 0.3989422804014327f

typedef __attribute__((ext_vector_type(8))) short short8b;  // 8 bf16
typedef __attribute__((ext_vector_type(4))) float f32x4;

__device__ __forceinline__ void cvt_split8(const float* f, short8b& hi, short8b& lo) {
#pragma unroll
    for (int i = 0; i < 8; ++i) {
        unsigned u = __float_as_uint(f[i]);
        hi[i] = (short)(u >> 16);
        float r = f[i] - __uint_as_float(u & 0xFFFF0000u);
        lo[i] = (short)(__float_as_uint(r) >> 16);
    }
}
__device__ __forceinline__ unsigned short f2bf_rn(float x) {  // round-to-nearest-even
    unsigned u = __float_as_uint(x);
    return (unsigned short)((u + 0x7FFFu + ((u >> 16) & 1u)) >> 16);
}

// ---------------- Kernel A: prior + sig (R2-proven) ----------------
__global__ __launch_bounds__(256) void prior_kernel(
    const float* __restrict__ sigma, const float* __restrict__ dist,
    float* __restrict__ prior, float* __restrict__ sigout) {
    const int bid = blockIdx.x;
    const int b = bid >> 3, h = bid & 7;
    __shared__ float sgs[L_], c1s[L_], c2s[L_];
    const int t = threadIdx.x;
    if (t < L_) {
        float x = sigma[((size_t)b * L_ + t) * H_ + h];
        float s = 1.0f / (1.0f + exp2f(-5.0f * LOG2E * x)) + 1e-5f;
        float sg = expm1f(s * LN3);          // 3^s - 1, accurate near 0
        float inv = 1.0f / sg;
        sgs[t] = sg;
        c1s[t] = INV_SQRT_2PI * inv;
        c2s[t] = 0.5f * LOG2E * inv * inv;
    }
    __syncthreads();
    const size_t base4 = (size_t)(b * H_ + h) * (L_ * L_ / 4);
    const float4* d4 = (const float4*)dist;
    float4* p4 = (float4*)prior;
    float4* s4 = (float4*)sigout;
    for (int idx = t; idx < L_ * L_ / 4; idx += 256) {
        int l = idx / (L_ / 4);
        float c1 = c1s[l], c2 = c2s[l], sg = sgs[l];
        float4 d = d4[idx];
        float4 pr;
        pr.x = c1 * exp2f(-d.x * d.x * c2);
        pr.y = c1 * exp2f(-d.y * d.y * c2);
        pr.z = c1 * exp2f(-d.z * d.z * c2);
        pr.w = c1 * exp2f(-d.w * d.w * c2);
        p4[base4 + idx] = pr;
        s4[base4 + idx] = make_float4(sg, sg, sg, sg);
    }
}

// ---------------- Kernel B: scores via MFMA (R4-proven, verbatim) ----------
__global__ __launch_bounds__(256) void scores_kernel(
    const float* __restrict__ Q, const float* __restrict__ K,
    float* __restrict__ series, float* __restrict__ Mout) {
    const int bid = blockIdx.x;
    const int b = bid >> 3, h = bid & 7;
    __shared__ __align__(16) char smem[51456];
    float* den_s = (float*)(smem + 51200);
    const int t = threadIdx.x;

    // ---- stage Q, K as bf16 hi/lo (XOR-swizzled rows) ----
    for (int pass = 0; pass < 2; ++pass) {
        const float* Mt = pass ? K : Q;
        const int hioff = pass ? 0 : 25600;
        const int looff = pass ? 12800 : 38400;
        for (int ci = t; ci < 800; ci += 256) {
            int row = ci >> 3, c8 = ci & 7;
            const float* src = Mt + ((size_t)(b * L_ + row) * H_ + h) * E_ + c8 * 8;
            float4 f0 = *(const float4*)src;
            float4 f1 = *(const float4*)(src + 4);
            float f[8] = {f0.x, f0.y, f0.z, f0.w, f1.x, f1.y, f1.z, f1.w};
            short8b hi8, lo8;
            cvt_split8(f, hi8, lo8);
            int byte = (row * 128 + c8 * 16) ^ ((row & 7) << 4);
            *(short8b*)(smem + hioff + byte) = hi8;
            *(short8b*)(smem + looff + byte) = lo8;
        }
    }
    __syncthreads();

    const int wave = t >> 6;
    const int lane = t & 63;
    const int lr = lane & 15;   // tile row (P) / matrix col l-offset
    const int g  = lane >> 4;   // k-group

    // ---- B-frags (Q^T) for this wave's l-tiles; then Q region is dead ----
    const int nt = (wave < 3) ? 2 : 1;
    short8b qh[2][2], ql[2][2];
    for (int ti = 0; ti < nt; ++ti) {
        int lt = wave * 2 + ti;
        int lrow = lt * 16 + lr; if (lrow > 99) lrow = 99;
        int rb = lrow * 128, sw = (lrow & 7) << 4;
#pragma unroll
        for (int es = 0; es < 2; ++es) {
            int byte = (rb + g * 16 + es * 64) ^ sw;
            qh[ti][es] = *(const short8b*)(smem + 25600 + byte);
            ql[ti][es] = *(const short8b*)(smem + 38400 + byte);
        }
    }
    __syncthreads();   // all B-frags loaded -> P staging may reuse Q region

    const float cs = 0.125f * LOG2E;
    const size_t bh = (size_t)(b * H_ + h);
    char* pbase = smem + 25600 + wave * 6400;   // [16][100] f32 per wave

    for (int ti = 0; ti < nt; ++ti) {
        const int lt = wave * 2 + ti;
        const int l = lt * 16 + lr;     // this lane's column (may be >=100)
        float m1 = -INFINITY, m2 = -INFINITY, sum1 = 0.f, sum2 = 0.f, den = 0.f;
        for (int jt = 0; jt < 7; ++jt) {
            int jrow = jt * 16 + lr; if (jrow > 99) jrow = 99;
            int rb = jrow * 128, sw = (jrow & 7) << 4;
            f32x4 C = {0.f, 0.f, 0.f, 0.f};
#pragma unroll
            for (int es = 0; es < 2; ++es) {
                int byte = (rb + g * 16 + es * 64) ^ sw;
                short8b kh = *(const short8b*)(smem + 0 + byte);
                short8b kl = *(const short8b*)(smem + 12800 + byte);
                C = __builtin_amdgcn_mfma_f32_16x16x32_bf16(kh, qh[ti][es], C, 0, 0, 0);
                C = __builtin_amdgcn_mfma_f32_16x16x32_bf16(kh, ql[ti][es], C, 0, 0, 0);
                C = __builtin_amdgcn_mfma_f32_16x16x32_bf16(kl, qh[ti][es], C, 0, 0, 0);
            }
            f32x4 pw = {0.f, 0.f, 0.f, 0.f};
#pragma unroll
            for (int r = 0; r < 4; ++r) {
                int j = jt * 16 + g * 4 + r;
                float s = C[r];
                if (j < 100) {
                    m1 = fmaxf(m1, s);
                    sum1 += s;
                    bool band = (j - l < 3) && (l - j < 3);
                    float sp = band ? 0.f : s;
                    m2 = fmaxf(m2, sp);
                    sum2 += sp;
                    float p = exp2f(s * cs);
                    den += p;                       // diag included in den
                    pw[r] = (j == l) ? 0.f : p;     // diag zeroed in output
                }
            }
            if (!(jt == 6 && g > 0))
                *(f32x4*)(pbase + lr * 400 + jt * 64 + g * 16) = pw;
        }
        m1   = fmaxf(m1, __shfl_xor(m1, 16, 64));
        m1   = fmaxf(m1, __shfl_xor(m1, 32, 64));
        m2   = fmaxf(m2, __shfl_xor(m2, 16, 64));
        m2   = fmaxf(m2, __shfl_xor(m2, 32, 64));
        sum1 += __shfl_xor(sum1, 16, 64);
        sum1 += __shfl_xor(sum1, 32, 64);
        sum2 += __shfl_xor(sum2, 16, 64);
        sum2 += __shfl_xor(sum2, 32, 64);
        den  += __shfl_xor(den, 16, 64);
        den  += __shfl_xor(den, 32, 64);
        if (lane < 16 && l < 100) {
            den_s[wave * 16 + lr] = den;
            float M1 = m1 - sum1 * (1.0f / 100.0f);
            float M2 = m2 - sum2 * (1.0f / 94.0f);
            Mout[bh * L_ + l] = M1 - M2;
        }
        for (int f = lane; f < 400; f += 64) {
            int row = f / 25, c = f - row * 25;
            int lg = lt * 16 + row;
            if (lg < 100) {
                f32x4 p = *(const f32x4*)(pbase + row * 400 + c * 16);
                float invd = 1.0f / den_s[wave * 16 + row];
                p.x *= invd; p.y *= invd; p.z *= invd; p.w *= invd;
                *(f32x4*)(series + (bh * L_ + lg) * L_ + c * 4) = p;
            }
        }
    }
}

// ---------------- Kernel C: (PV)^T = V^T . series^T via bf16 MFMA ----------
// V^T staged bf16 [64 d][104 j] (208B rows) in 13 KB LDS; series rows read
// per-lane from global (already normalized + diag-zeroed -> MFMA result is
// final). k-tail (j>=100): V^T cols zeroed; jt32==3,g>0 slices use clamped
// in-row address + zero B-frag (contributes exactly 0).
__global__ __launch_bounds__(256) void pv_kernel(
    const float* __restrict__ Vin, const float* __restrict__ series,
    float* __restrict__ Vout) {
    const int bid = blockIdx.x;
    const int b = bid >> 3, h = bid & 7;
    __shared__ __align__(16) unsigned short VT[64 * 104];  // 13312 B
    const int t = threadIdx.x;
    for (int f = t; f < 1600; f += 256) {
        int j = f >> 4, c = f & 15;
        float4 v = *(const float4*)(Vin + ((size_t)(b * L_ + j) * H_ + h) * D_ + c * 4);
        float vv[4] = {v.x, v.y, v.z, v.w};
#pragma unroll
        for (int i = 0; i < 4; ++i)
            VT[(c * 4 + i) * 104 + j] = f2bf_rn(vv[i]);
    }
    if (t < 64) {   // zero cols 100..103
        VT[t * 104 + 100] = 0; VT[t * 104 + 101] = 0;
        VT[t * 104 + 102] = 0; VT[t * 104 + 103] = 0;
    }
    __syncthreads();

    const int wave = t >> 6;
    const int lane = t & 63;
    const int lr = lane & 15;
    const int g  = lane >> 4;
    const int nt = (wave < 3) ? 2 : 1;
    const size_t bh = (size_t)(b * H_ + h);

    for (int ti = 0; ti < nt; ++ti) {
        const int lt = wave * 2 + ti;
        const int l = lt * 16 + lr;
        const int lrow = (l < 100) ? l : 99;
        const float* prow = series + (bh * L_ + lrow) * L_;
        f32x4 acc[4] = {{0.f,0.f,0.f,0.f},{0.f,0.f,0.f,0.f},
                        {0.f,0.f,0.f,0.f},{0.f,0.f,0.f,0.f}};
#pragma unroll
        for (int jt32 = 0; jt32 < 4; ++jt32) {
            const bool tail = (jt32 == 3) && (g > 0);
            const int j0 = tail ? 96 : (jt32 * 32 + g * 8);
            short8b Bp = {0, 0, 0, 0, 0, 0, 0, 0};
            if (!tail) {
                if (jt32 < 3) {
                    float4 f0 = *(const float4*)(prow + j0);
                    float4 f1 = *(const float4*)(prow + j0 + 4);
                    float f[8] = {f0.x, f0.y, f0.z, f0.w, f1.x, f1.y, f1.z, f1.w};
#pragma unroll
                    for (int i = 0; i < 8; ++i) Bp[i] = (short)f2bf_rn(f[i]);
                } else {   // g==0: j 96..99 real, 100..103 zero
                    float4 f0 = *(const float4*)(prow + 96);
                    float f[4] = {f0.x, f0.y, f0.z, f0.w};
#pragma unroll
                    for (int i = 0; i < 4; ++i) Bp[i] = (short)f2bf_rn(f[i]);
                }
            }
#pragma unroll
            for (int dt = 0; dt < 4; ++dt) {
                int d = dt * 16 + lr;
                short8b Av = *(const short8b*)(&VT[d * 104 + j0]);
                acc[dt] = __builtin_amdgcn_mfma_f32_16x16x32_bf16(Av, Bp, acc[dt], 0, 0, 0);
            }
        }
        if (l < 100) {
#pragma unroll
            for (int dt = 0; dt < 4; ++dt)
                // lane holds out[l][dt*16 + g*4 .. +3]
                *(f32x4*)(Vout + ((size_t)(b * L_ + l) * H_ + h) * D_ + dt * 16 + g * 4) = acc[dt];
        }
    }
}

extern "C" void kernel_launch(void* const* d_in, const int* in_sizes, int n_in,
                              void* d_out, int out_size, void* d_ws, size_t ws_size,
                              hipStream_t stream) {
    const float* Q     = (const float*)d_in[0];
    const float* K     = (const float*)d_in[1];
    const float* V     = (const float*)d_in[2];
    const float* sigma = (const float*)d_in[3];
    const float* dist  = (const float*)d_in[4];

    float* out    = (float*)d_out;
    float* Vout   = out;
    float* series = out + OFF_SERIES;
    float* prior  = out + OFF_PRIOR;
    float* sigout = out + OFF_SIG;
    float* Mout   = out + OFF_M;

    dim3 grid(B_ * H_), block(256);
    hipLaunchKernelGGL(scores_kernel, grid, block, 0, stream, Q, K, series, Mout);
    hipLaunchKernelGGL(pv_kernel,     grid, block, 0, stream, V, series, Vout);
    hipLaunchKernelGGL(prior_kernel,  grid, block, 0, stream, sigma, dist, prior, sigout);
}

// Round 9
// 131.425 us; speedup vs baseline: 2.9996x; 1.5544x over previous
//
#include <hip/hip_runtime.h>
#include <math.h>

#define B_ 256
#define L_ 100
#define H_ 8
#define E_ 64
#define D_ 64

// Output offsets (floats): V[B,L,H,D], series[B,H,L,L], prior, sig, M[B,H,L]
#define OFF_SERIES ((size_t)B_ * L_ * H_ * D_)
#define OFF_PRIOR  (OFF_SERIES + (size_t)B_ * H_ * L_ * L_)
#define OFF_SIG    (OFF_PRIOR  + (size_t)B_ * H_ * L_ * L_)
#define OFF_M      (OFF_SIG    + (size_t)B_ * H_ * L_ * L_)

#define LOG2E 1.4426950408889634f
#define LN3   1.0986122886681098f
#define INV_SQRT_2PI 0.3989422804014327f

typedef __attribute__((ext_vector_type(8))) short short8b;  // 8 bf16
typedef __attribute__((ext_vector_type(4))) float f32x4;

__device__ __forceinline__ void cvt_split8(const float* f, short8b& hi, short8b& lo) {
#pragma unroll
    for (int i = 0; i < 8; ++i) {
        unsigned u = __float_as_uint(f[i]);
        hi[i] = (short)(u >> 16);
        float r = f[i] - __uint_as_float(u & 0xFFFF0000u);
        lo[i] = (short)(__float_as_uint(r) >> 16);
    }
}
__device__ __forceinline__ unsigned short f2bf_rn(float x) {  // round-to-nearest-even
    unsigned u = __float_as_uint(x);
    return (unsigned short)((u + 0x7FFFu + ((u >> 16) & 1u)) >> 16);
}
__device__ __forceinline__ float bf2f(unsigned short v) {
    return __uint_as_float((unsigned)v << 16);
}

// ---------------- Kernel A: prior + sig (R2-proven) ----------------
__global__ __launch_bounds__(256) void prior_kernel(
    const float* __restrict__ sigma, const float* __restrict__ dist,
    float* __restrict__ prior, float* __restrict__ sigout) {
    const int bid = blockIdx.x;
    const int b = bid >> 3, h = bid & 7;
    __shared__ float sgs[L_], c1s[L_], c2s[L_];
    const int t = threadIdx.x;
    if (t < L_) {
        float x = sigma[((size_t)b * L_ + t) * H_ + h];
        float s = 1.0f / (1.0f + exp2f(-5.0f * LOG2E * x)) + 1e-5f;
        float sg = expm1f(s * LN3);          // 3^s - 1, accurate near 0
        float inv = 1.0f / sg;
        sgs[t] = sg;
        c1s[t] = INV_SQRT_2PI * inv;
        c2s[t] = 0.5f * LOG2E * inv * inv;
    }
    __syncthreads();
    const size_t base4 = (size_t)(b * H_ + h) * (L_ * L_ / 4);
    const float4* d4 = (const float4*)dist;
    float4* p4 = (float4*)prior;
    float4* s4 = (float4*)sigout;
    for (int idx = t; idx < L_ * L_ / 4; idx += 256) {
        int l = idx / (L_ / 4);
        float c1 = c1s[l], c2 = c2s[l], sg = sgs[l];
        float4 d = d4[idx];
        float4 pr;
        pr.x = c1 * exp2f(-d.x * d.x * c2);
        pr.y = c1 * exp2f(-d.y * d.y * c2);
        pr.z = c1 * exp2f(-d.z * d.z * c2);
        pr.w = c1 * exp2f(-d.w * d.w * c2);
        p4[base4 + idx] = pr;
        s4[base4 + idx] = make_float4(sg, sg, sg, sg);
    }
}

// ------- Kernel B: scores via MFMA, one tile per wave, reg-buffered P ------
// Grid = 2*B*H: block (bh, half). half0 -> l-tiles 0..3, half1 -> 4..6.
// K staged hi/lo split-bf16 in 25.6 KB LDS (XOR swizzle, R4-proven layout).
// Q B-frags per-lane from GLOBAL (VMEM) + register split. P kept as packed
// bf16 in 7 uint2 regs; den is all-lane after the ^16/^32 reduce -> lane-
// local normalize + direct f32x4 stores (4 g-lanes form 64B chunks per row).
__global__ __launch_bounds__(256) void scores_kernel(
    const float* __restrict__ Q, const float* __restrict__ K,
    float* __restrict__ series, float* __restrict__ Mout) {
    const int bid = blockIdx.x;
    const int half = bid & 1;
    const int bh   = bid >> 1;
    const int b = bh >> 3, h = bh & 7;
    __shared__ __align__(16) char smem[25600];   // KHI @0, KLO @12800
    const int t = threadIdx.x;

    // ---- stage K as split-bf16 hi/lo (row XOR-swizzle) ----
    for (int ci = t; ci < 800; ci += 256) {
        int row = ci >> 3, c8 = ci & 7;
        const float* src = K + ((size_t)(b * L_ + row) * H_ + h) * E_ + c8 * 8;
        float4 f0 = *(const float4*)src;
        float4 f1 = *(const float4*)(src + 4);
        float f[8] = {f0.x, f0.y, f0.z, f0.w, f1.x, f1.y, f1.z, f1.w};
        short8b hi8, lo8;
        cvt_split8(f, hi8, lo8);
        int byte = (row * 128 + c8 * 16) ^ ((row & 7) << 4);
        *(short8b*)(smem + byte) = hi8;
        *(short8b*)(smem + 12800 + byte) = lo8;
    }

    const int wave = t >> 6;
    const int lane = t & 63;
    const int lr = lane & 15;   // l-offset within tile (MFMA col)
    const int g  = lane >> 4;   // k-group (MFMA row block)
    const int lt = half * 4 + wave;      // tile index 0..7
    const bool active = (lt < 7);
    const int l = lt * 16 + lr;          // query row (may be >=100)

    // ---- Q B-frags from global + register split (independent of LDS) ----
    short8b qh[2], ql[2];
    if (active) {
        const int lrow = (l < 100) ? l : 99;
        const float* qp = Q + ((size_t)(b * L_ + lrow) * H_ + h) * E_;
#pragma unroll
        for (int es = 0; es < 2; ++es) {
            float4 f0 = *(const float4*)(qp + es * 32 + g * 8);
            float4 f1 = *(const float4*)(qp + es * 32 + g * 8 + 4);
            float f[8] = {f0.x, f0.y, f0.z, f0.w, f1.x, f1.y, f1.z, f1.w};
            cvt_split8(f, qh[es], ql[es]);
        }
    }
    __syncthreads();

    if (!active) return;

    const float cs = 0.125f * LOG2E;
    float m1 = -INFINITY, m2 = -INFINITY, sum1 = 0.f, sum2 = 0.f, den = 0.f;
    uint2 pk[7];
#pragma unroll
    for (int jt = 0; jt < 7; ++jt) {
        int jrow = jt * 16 + lr; if (jrow > 99) jrow = 99;
        int rb = jrow * 128, sw = (jrow & 7) << 4;
        f32x4 C = {0.f, 0.f, 0.f, 0.f};
#pragma unroll
        for (int es = 0; es < 2; ++es) {
            int byte = (rb + g * 16 + es * 64) ^ sw;
            short8b kh = *(const short8b*)(smem + byte);
            short8b kl = *(const short8b*)(smem + 12800 + byte);
            C = __builtin_amdgcn_mfma_f32_16x16x32_bf16(kh, qh[es], C, 0, 0, 0);
            C = __builtin_amdgcn_mfma_f32_16x16x32_bf16(kh, ql[es], C, 0, 0, 0);
            C = __builtin_amdgcn_mfma_f32_16x16x32_bf16(kl, qh[es], C, 0, 0, 0);
        }
        unsigned short pw[4] = {0, 0, 0, 0};
#pragma unroll
        for (int r = 0; r < 4; ++r) {
            int j = jt * 16 + g * 4 + r;
            float s = C[r];
            if (j < 100) {
                m1 = fmaxf(m1, s);
                sum1 += s;
                bool band = (j - l < 3) && (l - j < 3);
                float sp = band ? 0.f : s;
                m2 = fmaxf(m2, sp);
                sum2 += sp;
                float p = exp2f(s * cs);
                den += p;                           // diag included in den
                pw[r] = (j == l) ? 0 : f2bf_rn(p);  // diag zeroed in output
            }
        }
        pk[jt].x = (unsigned)pw[0] | ((unsigned)pw[1] << 16);
        pk[jt].y = (unsigned)pw[2] | ((unsigned)pw[3] << 16);
    }
    // combine the 4 k-groups (lanes ^16, ^32) -> every lane holds full stats
    m1   = fmaxf(m1, __shfl_xor(m1, 16, 64));
    m1   = fmaxf(m1, __shfl_xor(m1, 32, 64));
    m2   = fmaxf(m2, __shfl_xor(m2, 16, 64));
    m2   = fmaxf(m2, __shfl_xor(m2, 32, 64));
    sum1 += __shfl_xor(sum1, 16, 64);
    sum1 += __shfl_xor(sum1, 32, 64);
    sum2 += __shfl_xor(sum2, 16, 64);
    sum2 += __shfl_xor(sum2, 32, 64);
    den  += __shfl_xor(den, 16, 64);
    den  += __shfl_xor(den, 32, 64);
    const float invd = 1.0f / den;

    if (lane < 16 && l < 100) {
        float M1 = m1 - sum1 * (1.0f / 100.0f);
        float M2 = m2 - sum2 * (1.0f / 94.0f);
        Mout[(size_t)bh * L_ + l] = M1 - M2;
    }
    if (l < 100) {
        float* srow = series + ((size_t)bh * L_ + l) * L_;
#pragma unroll
        for (int jt = 0; jt < 7; ++jt) {
            if (jt < 6 || g == 0) {   // j >= 100 slices skipped
                f32x4 p;
                p.x = bf2f((unsigned short)(pk[jt].x & 0xFFFF)) * invd;
                p.y = bf2f((unsigned short)(pk[jt].x >> 16))    * invd;
                p.z = bf2f((unsigned short)(pk[jt].y & 0xFFFF)) * invd;
                p.w = bf2f((unsigned short)(pk[jt].y >> 16))    * invd;
                *(f32x4*)(srow + jt * 16 + g * 4) = p;
            }
        }
    }
}

// ---------------- Kernel C: (PV)^T = V^T . series^T via bf16 MFMA ----------
__global__ __launch_bounds__(256) void pv_kernel(
    const float* __restrict__ Vin, const float* __restrict__ series,
    float* __restrict__ Vout) {
    const int bid = blockIdx.x;
    const int b = bid >> 3, h = bid & 7;
    __shared__ __align__(16) unsigned short VT[64 * 104];  // 13312 B
    const int t = threadIdx.x;
    for (int f = t; f < 1600; f += 256) {
        int j = f >> 4, c = f & 15;
        float4 v = *(const float4*)(Vin + ((size_t)(b * L_ + j) * H_ + h) * D_ + c * 4);
        float vv[4] = {v.x, v.y, v.z, v.w};
#pragma unroll
        for (int i = 0; i < 4; ++i)
            VT[(c * 4 + i) * 104 + j] = f2bf_rn(vv[i]);
    }
    if (t < 64) {   // zero cols 100..103
        VT[t * 104 + 100] = 0; VT[t * 104 + 101] = 0;
        VT[t * 104 + 102] = 0; VT[t * 104 + 103] = 0;
    }
    __syncthreads();

    const int wave = t >> 6;
    const int lane = t & 63;
    const int lr = lane & 15;
    const int g  = lane >> 4;
    const int nt = (wave < 3) ? 2 : 1;
    const size_t bh = (size_t)(b * H_ + h);

    for (int ti = 0; ti < nt; ++ti) {
        const int lt = wave * 2 + ti;
        const int l = lt * 16 + lr;
        const int lrow = (l < 100) ? l : 99;
        const float* prow = series + (bh * L_ + lrow) * L_;
        f32x4 acc[4] = {{0.f,0.f,0.f,0.f},{0.f,0.f,0.f,0.f},
                        {0.f,0.f,0.f,0.f},{0.f,0.f,0.f,0.f}};
#pragma unroll
        for (int jt32 = 0; jt32 < 4; ++jt32) {
            const bool tail = (jt32 == 3) && (g > 0);
            const int j0 = tail ? 96 : (jt32 * 32 + g * 8);
            short8b Bp = {0, 0, 0, 0, 0, 0, 0, 0};
            if (!tail) {
                if (jt32 < 3) {
                    float4 f0 = *(const float4*)(prow + j0);
                    float4 f1 = *(const float4*)(prow + j0 + 4);
                    float f[8] = {f0.x, f0.y, f0.z, f0.w, f1.x, f1.y, f1.z, f1.w};
#pragma unroll
                    for (int i = 0; i < 8; ++i) Bp[i] = (short)f2bf_rn(f[i]);
                } else {   // g==0: j 96..99 real, 100..103 zero
                    float4 f0 = *(const float4*)(prow + 96);
                    float f[4] = {f0.x, f0.y, f0.z, f0.w};
#pragma unroll
                    for (int i = 0; i < 4; ++i) Bp[i] = (short)f2bf_rn(f[i]);
                }
            }
#pragma unroll
            for (int dt = 0; dt < 4; ++dt) {
                int d = dt * 16 + lr;
                short8b Av = *(const short8b*)(&VT[d * 104 + j0]);
                acc[dt] = __builtin_amdgcn_mfma_f32_16x16x32_bf16(Av, Bp, acc[dt], 0, 0, 0);
            }
        }
        if (l < 100) {
#pragma unroll
            for (int dt = 0; dt < 4; ++dt)
                *(f32x4*)(Vout + ((size_t)(b * L_ + l) * H_ + h) * D_ + dt * 16 + g * 4) = acc[dt];
        }
    }
}

extern "C" void kernel_launch(void* const* d_in, const int* in_sizes, int n_in,
                              void* d_out, int out_size, void* d_ws, size_t ws_size,
                              hipStream_t stream) {
    const float* Q     = (const float*)d_in[0];
    const float* K     = (const float*)d_in[1];
    const float* V     = (const float*)d_in[2];
    const float* sigma = (const float*)d_in[3];
    const float* dist  = (const float*)d_in[4];

    float* out    = (float*)d_out;
    float* Vout   = out;
    float* series = out + OFF_SERIES;
    float* prior  = out + OFF_PRIOR;
    float* sigout = out + OFF_SIG;
    float* Mout   = out + OFF_M;

    hipLaunchKernelGGL(scores_kernel, dim3(2 * B_ * H_), dim3(256), 0, stream, Q, K, series, Mout);
    hipLaunchKernelGGL(pv_kernel,     dim3(B_ * H_),     dim3(256), 0, stream, V, series, Vout);
    hipLaunchKernelGGL(prior_kernel,  dim3(B_ * H_),     dim3(256), 0, stream, sigma, dist, prior, sigout);
}

// Round 10
// 124.115 us; speedup vs baseline: 3.1763x; 1.0589x over previous
//
#include <hip/hip_runtime.h>
#include <math.h>

#define B_ 256
#define L_ 100
#define H_ 8
#define E_ 64
#define D_ 64

// Output offsets (floats): V[B,L,H,D], series[B,H,L,L], prior, sig, M[B,H,L]
#define OFF_SERIES ((size_t)B_ * L_ * H_ * D_)
#define OFF_PRIOR  (OFF_SERIES + (size_t)B_ * H_ * L_ * L_)
#define OFF_SIG    (OFF_PRIOR  + (size_t)B_ * H_ * L_ * L_)
#define OFF_M      (OFF_SIG    + (size_t)B_ * H_ * L_ * L_)

#define LOG2E 1.4426950408889634f
#define LN3   1.0986122886681098f
#define INV_SQRT_2PI 0.3989422804014327f

typedef __attribute__((ext_vector_type(8))) short short8b;  // 8 bf16
typedef __attribute__((ext_vector_type(4))) float f32x4;

// LDS layout (bytes)
#define KHI 0        // K hi bf16 [100][64], 128B rows, XOR swizzle: 12800
#define KLO 12800    // K lo bf16: 12800
#define VT  25600    // V^T bf16 [64 d][120 j] (240B rows, 16B-aligned): 15360
#define SMEM_BYTES 40960   // 40 KB -> 4 blocks/CU (LDS-wise)

__device__ __forceinline__ void cvt_split8(const float* f, short8b& hi, short8b& lo) {
#pragma unroll
    for (int i = 0; i < 8; ++i) {
        unsigned u = __float_as_uint(f[i]);
        hi[i] = (short)(u >> 16);
        float r = f[i] - __uint_as_float(u & 0xFFFF0000u);
        lo[i] = (short)(__float_as_uint(r) >> 16);
    }
}
__device__ __forceinline__ unsigned short f2bf_rn(float x) {  // round-to-nearest-even
    unsigned u = __float_as_uint(x);
    return (unsigned short)((u + 0x7FFFu + ((u >> 16) & 1u)) >> 16);
}
__device__ __forceinline__ float bf2f(unsigned short v) {
    return __uint_as_float((unsigned)v << 16);
}

// One fused kernel: grid = 2*B*H (2 half-blocks per (b,h)).
// half0 -> l-tiles 0..3, half1 -> l-tiles 4..6 (wave3 idle in compute).
// Phase 1: stage K split-bf16 (hi/lo, XOR swizzle) + V^T bf16 [64][120].
// Phase 2 (per wave, 1 l-tile): QK^T MFMA -> stats -> pk regs -> reduce ->
//          M + normalized series stores (R9-proven).
// Phase 3: PV via MFMA; B-frags gathered from pk regs of sibling lanes with
//          4 shuffles per 32-k block (no P LDS region, no extra barrier).
// Phase 4: prior+sig tail, half the (b,h) tile per block (write-bound,
//          overlaps other blocks' compute).
__global__ __launch_bounds__(256) void fused_kernel(
    const float* __restrict__ Q, const float* __restrict__ K,
    const float* __restrict__ Vin, const float* __restrict__ sigma,
    const float* __restrict__ dist, float* __restrict__ Vout,
    float* __restrict__ series, float* __restrict__ prior,
    float* __restrict__ sigout, float* __restrict__ Mout) {
    const int bid = blockIdx.x;
    const int half = bid & 1;
    const int bh   = bid >> 1;
    const int b = bh >> 3, h = bh & 7;
    __shared__ __align__(16) char smem[SMEM_BYTES];
    const int t = threadIdx.x;

    // ---- stage K as split-bf16 hi/lo (row XOR-swizzle, R4-proven) ----
    for (int ci = t; ci < 800; ci += 256) {
        int row = ci >> 3, c8 = ci & 7;
        const float* src = K + ((size_t)(b * L_ + row) * H_ + h) * E_ + c8 * 8;
        float4 f0 = *(const float4*)src;
        float4 f1 = *(const float4*)(src + 4);
        float f[8] = {f0.x, f0.y, f0.z, f0.w, f1.x, f1.y, f1.z, f1.w};
        short8b hi8, lo8;
        cvt_split8(f, hi8, lo8);
        int byte = (row * 128 + c8 * 16) ^ ((row & 7) << 4);
        *(short8b*)(smem + KHI + byte) = hi8;
        *(short8b*)(smem + KLO + byte) = lo8;
    }
    // ---- stage V^T bf16 [64][120], two j-columns per u32 write ----
    for (int f = t; f < 800; f += 256) {
        int j2 = f >> 4, c = f & 15;   // j2: 0..49, c: 0..15
        const float* vp = Vin + ((size_t)(b * L_ + 2 * j2) * H_ + h) * D_ + c * 4;
        float4 v0 = *(const float4*)vp;
        float4 v1 = *(const float4*)(vp + H_ * D_);
        float a0[4] = {v0.x, v0.y, v0.z, v0.w};
        float a1[4] = {v1.x, v1.y, v1.z, v1.w};
#pragma unroll
        for (int i = 0; i < 4; ++i) {
            unsigned pkd = (unsigned)f2bf_rn(a0[i]) | ((unsigned)f2bf_rn(a1[i]) << 16);
            *(unsigned*)(smem + VT + (c * 4 + i) * 240 + j2 * 4) = pkd;
        }
    }
    if (t < 64) {   // zero cols 100..105 (k-tail reads cover <=103)
        *(unsigned*)(smem + VT + t * 240 + 200) = 0;
        *(unsigned*)(smem + VT + t * 240 + 204) = 0;
        *(unsigned*)(smem + VT + t * 240 + 208) = 0;
    }

    const int wave = t >> 6;
    const int lane = t & 63;
    const int lr = lane & 15;   // l-offset in tile (MFMA col)
    const int g  = lane >> 4;   // k-group
    const int lt = half * 4 + wave;
    const bool active = (lt < 7);
    const int l = lt * 16 + lr;

    // ---- Q B-frags from global (VMEM, no LDS dep) + register split ----
    short8b qh[2], ql[2];
    if (active) {
        const int lrow = (l < 100) ? l : 99;
        const float* qp = Q + ((size_t)(b * L_ + lrow) * H_ + h) * E_;
#pragma unroll
        for (int es = 0; es < 2; ++es) {
            float4 f0 = *(const float4*)(qp + es * 32 + g * 8);
            float4 f1 = *(const float4*)(qp + es * 32 + g * 8 + 4);
            float f[8] = {f0.x, f0.y, f0.z, f0.w, f1.x, f1.y, f1.z, f1.w};
            cvt_split8(f, qh[es], ql[es]);
        }
    }
    __syncthreads();

    if (active) {
        const float cs = 0.125f * LOG2E;
        float m1 = -INFINITY, m2 = -INFINITY, sum1 = 0.f, sum2 = 0.f, den = 0.f;
        uint2 pk[7];
#pragma unroll
        for (int jt = 0; jt < 7; ++jt) {
            int jrow = jt * 16 + lr; if (jrow > 99) jrow = 99;
            int rb = jrow * 128, sw = (jrow & 7) << 4;
            f32x4 C = {0.f, 0.f, 0.f, 0.f};
#pragma unroll
            for (int es = 0; es < 2; ++es) {
                int byte = (rb + g * 16 + es * 64) ^ sw;
                short8b kh = *(const short8b*)(smem + KHI + byte);
                short8b kl = *(const short8b*)(smem + KLO + byte);
                C = __builtin_amdgcn_mfma_f32_16x16x32_bf16(kh, qh[es], C, 0, 0, 0);
                C = __builtin_amdgcn_mfma_f32_16x16x32_bf16(kh, ql[es], C, 0, 0, 0);
                C = __builtin_amdgcn_mfma_f32_16x16x32_bf16(kl, qh[es], C, 0, 0, 0);
            }
            unsigned short pw[4] = {0, 0, 0, 0};
#pragma unroll
            for (int r = 0; r < 4; ++r) {
                int j = jt * 16 + g * 4 + r;
                float s = C[r];
                if (j < 100) {
                    m1 = fmaxf(m1, s);
                    sum1 += s;
                    bool band = (j - l < 3) && (l - j < 3);
                    float sp = band ? 0.f : s;
                    m2 = fmaxf(m2, sp);
                    sum2 += sp;
                    float p = exp2f(s * cs);
                    den += p;                           // diag included in den
                    pw[r] = (j == l) ? 0 : f2bf_rn(p);  // diag zeroed in output
                }
            }
            pk[jt].x = (unsigned)pw[0] | ((unsigned)pw[1] << 16);
            pk[jt].y = (unsigned)pw[2] | ((unsigned)pw[3] << 16);
        }
        // combine the 4 k-groups -> every lane holds full stats for its lr
        m1   = fmaxf(m1, __shfl_xor(m1, 16, 64));
        m1   = fmaxf(m1, __shfl_xor(m1, 32, 64));
        m2   = fmaxf(m2, __shfl_xor(m2, 16, 64));
        m2   = fmaxf(m2, __shfl_xor(m2, 32, 64));
        sum1 += __shfl_xor(sum1, 16, 64);
        sum1 += __shfl_xor(sum1, 32, 64);
        sum2 += __shfl_xor(sum2, 16, 64);
        sum2 += __shfl_xor(sum2, 32, 64);
        den  += __shfl_xor(den, 16, 64);
        den  += __shfl_xor(den, 32, 64);
        const float invd = 1.0f / den;

        if (lane < 16 && l < 100) {
            float M1 = m1 - sum1 * (1.0f / 100.0f);
            float M2 = m2 - sum2 * (1.0f / 94.0f);
            Mout[(size_t)bh * L_ + l] = M1 - M2;
        }
        if (l < 100) {
            float* srow = series + ((size_t)bh * L_ + l) * L_;
#pragma unroll
            for (int jt = 0; jt < 7; ++jt) {
                if (jt < 6 || g == 0) {
                    f32x4 p;
                    p.x = bf2f((unsigned short)(pk[jt].x & 0xFFFF)) * invd;
                    p.y = bf2f((unsigned short)(pk[jt].x >> 16))    * invd;
                    p.z = bf2f((unsigned short)(pk[jt].y & 0xFFFF)) * invd;
                    p.w = bf2f((unsigned short)(pk[jt].y >> 16))    * invd;
                    *(f32x4*)(srow + jt * 16 + g * 4) = p;
                }
            }
        }

        // ---- PV: D[d][l] = sum_j V^T[d][j] P[l][j]; B-frags via shuffles --
        // target lane (lr,g), k-block jt32 needs P[l'][jt32*32+g*8 .. +7]
        // for column l' = lt*16+lr: held in pk[jt32*2+(g>>1)] of lanes
        // (lr, (g&1)*2) and (lr, (g&1)*2+1). j>=100 entries are 0 in pk.
        {
            f32x4 acc[4] = {{0.f,0.f,0.f,0.f},{0.f,0.f,0.f,0.f},
                            {0.f,0.f,0.f,0.f},{0.f,0.f,0.f,0.f}};
            const int src = lr + ((g & 1) << 5);
#pragma unroll
            for (int jt32 = 0; jt32 < 4; ++jt32) {
                uint2 sel;
                if (jt32 < 3) {
                    sel = (g & 2) ? pk[jt32 * 2 + 1] : pk[jt32 * 2];
                } else {  // pk[7] doesn't exist; those j>=112 are all zero
                    uint2 z; z.x = 0; z.y = 0;
                    sel = (g & 2) ? z : pk[6];
                }
                unsigned b0 = (unsigned)__shfl((int)sel.x, src, 64);
                unsigned b1 = (unsigned)__shfl((int)sel.y, src, 64);
                unsigned b2 = (unsigned)__shfl((int)sel.x, src + 16, 64);
                unsigned b3 = (unsigned)__shfl((int)sel.y, src + 16, 64);
                union { unsigned u[4]; short8b s; } bb;
                bb.u[0] = b0; bb.u[1] = b1; bb.u[2] = b2; bb.u[3] = b3;
                const int j0 = (jt32 == 3) ? 96 : (jt32 * 32 + g * 8);
#pragma unroll
                for (int dt = 0; dt < 4; ++dt) {
                    const char* ap = smem + VT + (dt * 16 + lr) * 240 + j0 * 2;
                    short8b Av = *(const short8b*)ap;
                    acc[dt] = __builtin_amdgcn_mfma_f32_16x16x32_bf16(Av, bb.s, acc[dt], 0, 0, 0);
                }
            }
            if (l < 100) {
#pragma unroll
                for (int dt = 0; dt < 4; ++dt) {
                    f32x4 o = acc[dt];
                    o.x *= invd; o.y *= invd; o.z *= invd; o.w *= invd;
                    *(f32x4*)(Vout + ((size_t)(b * L_ + l) * H_ + h) * D_ + dt * 16 + g * 4) = o;
                }
            }
        }
    }

    // ---- prior + sig tail: this block covers half of the (b,h) tile ----
    {
        const size_t base4 = (size_t)bh * 2500;
        const float4* d4 = (const float4*)dist;
        float4* p4 = (float4*)prior;
        float4* s4 = (float4*)sigout;
        const int lo = half * 1250, hi = lo + 1250;
        for (int idx = lo + t; idx < hi; idx += 256) {
            int lrow = idx / 25;
            float x = sigma[((size_t)b * L_ + lrow) * H_ + h];
            float s = 1.0f / (1.0f + exp2f(-5.0f * LOG2E * x)) + 1e-5f;
            float sg = expm1f(s * LN3);   // 3^s - 1, accurate near 0
            float inv = 1.0f / sg;
            float c1 = INV_SQRT_2PI * inv;
            float c2 = 0.5f * LOG2E * inv * inv;
            float4 d = d4[idx];
            float4 pr;
            pr.x = c1 * exp2f(-d.x * d.x * c2);
            pr.y = c1 * exp2f(-d.y * d.y * c2);
            pr.z = c1 * exp2f(-d.z * d.z * c2);
            pr.w = c1 * exp2f(-d.w * d.w * c2);
            p4[base4 + idx] = pr;
            s4[base4 + idx] = make_float4(sg, sg, sg, sg);
        }
    }
}

extern "C" void kernel_launch(void* const* d_in, const int* in_sizes, int n_in,
                              void* d_out, int out_size, void* d_ws, size_t ws_size,
                              hipStream_t stream) {
    const float* Q     = (const float*)d_in[0];
    const float* K     = (const float*)d_in[1];
    const float* V     = (const float*)d_in[2];
    const float* sigma = (const float*)d_in[3];
    const float* dist  = (const float*)d_in[4];

    float* out    = (float*)d_out;
    float* Vout   = out;
    float* series = out + OFF_SERIES;
    float* prior  = out + OFF_PRIOR;
    float* sigout = out + OFF_SIG;
    float* Mout   = out + OFF_M;

    hipLaunchKernelGGL(fused_kernel, dim3(2 * B_ * H_), dim3(256), 0, stream,
                       Q, K, V, sigma, dist, Vout, series, prior, sigout, Mout);
}

// Round 11
// 121.611 us; speedup vs baseline: 3.2416x; 1.0206x over previous
//
#include <hip/hip_runtime.h>
#include <math.h>

#define B_ 256
#define L_ 100
#define H_ 8
#define E_ 64
#define D_ 64

// Output offsets (floats): V[B,L,H,D], series[B,H,L,L], prior, sig, M[B,H,L]
#define OFF_SERIES ((size_t)B_ * L_ * H_ * D_)
#define OFF_PRIOR  (OFF_SERIES + (size_t)B_ * H_ * L_ * L_)
#define OFF_SIG    (OFF_PRIOR  + (size_t)B_ * H_ * L_ * L_)
#define OFF_M      (OFF_SIG    + (size_t)B_ * H_ * L_ * L_)

#define LOG2E 1.4426950408889634f
#define LN3   1.0986122886681098f
#define INV_SQRT_2PI 0.3989422804014327f

typedef __attribute__((ext_vector_type(8))) short short8b;  // 8 bf16
typedef __attribute__((ext_vector_type(4))) float f32x4;

// LDS layout (bytes)
#define KHI 0        // K hi bf16 [100][64], 128B rows, XOR swizzle: 12800
#define KLO 12800    // K lo bf16: 12800
#define VT  25600    // V^T bf16 [64 d][120 j] (240B rows, 16B-aligned): 15360
#define SMEM_BYTES 40960   // 40 KB -> 4 blocks/CU (LDS-wise)

__device__ __forceinline__ void cvt_split8(const float* f, short8b& hi, short8b& lo) {
#pragma unroll
    for (int i = 0; i < 8; ++i) {
        unsigned u = __float_as_uint(f[i]);
        hi[i] = (short)(u >> 16);
        float r = f[i] - __uint_as_float(u & 0xFFFF0000u);
        lo[i] = (short)(__float_as_uint(r) >> 16);
    }
}
__device__ __forceinline__ unsigned short f2bf_rn(float x) {  // round-to-nearest-even
    unsigned u = __float_as_uint(x);
    return (unsigned short)((u + 0x7FFFu + ((u >> 16) & 1u)) >> 16);
}
__device__ __forceinline__ float bf2f(unsigned short v) {
    return __uint_as_float((unsigned)v << 16);
}

// Fused kernel, grid = 2*B*H. XCD pair-swizzle: the two half-blocks of one
// (b,h) get dispatch indices 8 apart -> same XCD (bid%8) -> the second one's
// K/V reads hit that XCD's L2 instead of re-fetching HBM. All output stores
// are nontemporal (write-only data; keep L2 for K/V reuse).
__global__ __launch_bounds__(256) void fused_kernel(
    const float* __restrict__ Q, const float* __restrict__ K,
    const float* __restrict__ Vin, const float* __restrict__ sigma,
    const float* __restrict__ dist, float* __restrict__ Vout,
    float* __restrict__ series, float* __restrict__ prior,
    float* __restrict__ sigout, float* __restrict__ Mout) {
    const int bid = blockIdx.x;
    const int grp = bid >> 4;                 // 16 consecutive bids = 8 bh x 2 halves
    const int bh   = grp * 8 + (bid & 7);     // halves sit 8 apart -> same bid%8
    const int half = (bid >> 3) & 1;
    const int b = bh >> 3, h = bh & 7;
    __shared__ __align__(16) char smem[SMEM_BYTES];
    const int t = threadIdx.x;

    // ---- stage K as split-bf16 hi/lo (row XOR-swizzle, R4-proven) ----
    for (int ci = t; ci < 800; ci += 256) {
        int row = ci >> 3, c8 = ci & 7;
        const float* src = K + ((size_t)(b * L_ + row) * H_ + h) * E_ + c8 * 8;
        float4 f0 = *(const float4*)src;
        float4 f1 = *(const float4*)(src + 4);
        float f[8] = {f0.x, f0.y, f0.z, f0.w, f1.x, f1.y, f1.z, f1.w};
        short8b hi8, lo8;
        cvt_split8(f, hi8, lo8);
        int byte = (row * 128 + c8 * 16) ^ ((row & 7) << 4);
        *(short8b*)(smem + KHI + byte) = hi8;
        *(short8b*)(smem + KLO + byte) = lo8;
    }
    // ---- stage V^T bf16 [64][120], two j-columns per u32 write ----
    for (int f = t; f < 800; f += 256) {
        int j2 = f >> 4, c = f & 15;   // j2: 0..49, c: 0..15
        const float* vp = Vin + ((size_t)(b * L_ + 2 * j2) * H_ + h) * D_ + c * 4;
        float4 v0 = *(const float4*)vp;
        float4 v1 = *(const float4*)(vp + H_ * D_);
        float a0[4] = {v0.x, v0.y, v0.z, v0.w};
        float a1[4] = {v1.x, v1.y, v1.z, v1.w};
#pragma unroll
        for (int i = 0; i < 4; ++i) {
            unsigned pkd = (unsigned)f2bf_rn(a0[i]) | ((unsigned)f2bf_rn(a1[i]) << 16);
            *(unsigned*)(smem + VT + (c * 4 + i) * 240 + j2 * 4) = pkd;
        }
    }
    if (t < 64) {   // zero cols 100..105 (k-tail reads cover <=103)
        *(unsigned*)(smem + VT + t * 240 + 200) = 0;
        *(unsigned*)(smem + VT + t * 240 + 204) = 0;
        *(unsigned*)(smem + VT + t * 240 + 208) = 0;
    }

    const int wave = t >> 6;
    const int lane = t & 63;
    const int lr = lane & 15;   // l-offset in tile (MFMA col)
    const int g  = lane >> 4;   // k-group
    const int lt = half * 4 + wave;
    const bool active = (lt < 7);
    const int l = lt * 16 + lr;

    // ---- Q B-frags from global (VMEM, no LDS dep) + register split ----
    short8b qh[2], ql[2];
    if (active) {
        const int lrow = (l < 100) ? l : 99;
        const float* qp = Q + ((size_t)(b * L_ + lrow) * H_ + h) * E_;
#pragma unroll
        for (int es = 0; es < 2; ++es) {
            float4 f0 = *(const float4*)(qp + es * 32 + g * 8);
            float4 f1 = *(const float4*)(qp + es * 32 + g * 8 + 4);
            float f[8] = {f0.x, f0.y, f0.z, f0.w, f1.x, f1.y, f1.z, f1.w};
            cvt_split8(f, qh[es], ql[es]);
        }
    }
    __syncthreads();

    if (active) {
        const float cs = 0.125f * LOG2E;
        float m1 = -INFINITY, m2 = -INFINITY, sum1 = 0.f, sum2 = 0.f, den = 0.f;
        uint2 pk[7];
#pragma unroll
        for (int jt = 0; jt < 7; ++jt) {
            int jrow = jt * 16 + lr; if (jrow > 99) jrow = 99;
            int rb = jrow * 128, sw = (jrow & 7) << 4;
            f32x4 C = {0.f, 0.f, 0.f, 0.f};
#pragma unroll
            for (int es = 0; es < 2; ++es) {
                int byte = (rb + g * 16 + es * 64) ^ sw;
                short8b kh = *(const short8b*)(smem + KHI + byte);
                short8b kl = *(const short8b*)(smem + KLO + byte);
                C = __builtin_amdgcn_mfma_f32_16x16x32_bf16(kh, qh[es], C, 0, 0, 0);
                C = __builtin_amdgcn_mfma_f32_16x16x32_bf16(kh, ql[es], C, 0, 0, 0);
                C = __builtin_amdgcn_mfma_f32_16x16x32_bf16(kl, qh[es], C, 0, 0, 0);
            }
            unsigned short pw[4] = {0, 0, 0, 0};
#pragma unroll
            for (int r = 0; r < 4; ++r) {
                int j = jt * 16 + g * 4 + r;
                float s = C[r];
                if (j < 100) {
                    m1 = fmaxf(m1, s);
                    sum1 += s;
                    bool band = (j - l < 3) && (l - j < 3);
                    float sp = band ? 0.f : s;
                    m2 = fmaxf(m2, sp);
                    sum2 += sp;
                    float p = exp2f(s * cs);
                    den += p;                           // diag included in den
                    pw[r] = (j == l) ? 0 : f2bf_rn(p);  // diag zeroed in output
                }
            }
            pk[jt].x = (unsigned)pw[0] | ((unsigned)pw[1] << 16);
            pk[jt].y = (unsigned)pw[2] | ((unsigned)pw[3] << 16);
        }
        // combine the 4 k-groups -> every lane holds full stats for its lr
        m1   = fmaxf(m1, __shfl_xor(m1, 16, 64));
        m1   = fmaxf(m1, __shfl_xor(m1, 32, 64));
        m2   = fmaxf(m2, __shfl_xor(m2, 16, 64));
        m2   = fmaxf(m2, __shfl_xor(m2, 32, 64));
        sum1 += __shfl_xor(sum1, 16, 64);
        sum1 += __shfl_xor(sum1, 32, 64);
        sum2 += __shfl_xor(sum2, 16, 64);
        sum2 += __shfl_xor(sum2, 32, 64);
        den  += __shfl_xor(den, 16, 64);
        den  += __shfl_xor(den, 32, 64);
        const float invd = 1.0f / den;

        if (lane < 16 && l < 100) {
            float M1 = m1 - sum1 * (1.0f / 100.0f);
            float M2 = m2 - sum2 * (1.0f / 94.0f);
            __builtin_nontemporal_store(M1 - M2, Mout + (size_t)bh * L_ + l);
        }
        if (l < 100) {
            float* srow = series + ((size_t)bh * L_ + l) * L_;
#pragma unroll
            for (int jt = 0; jt < 7; ++jt) {
                if (jt < 6 || g == 0) {
                    f32x4 p;
                    p.x = bf2f((unsigned short)(pk[jt].x & 0xFFFF)) * invd;
                    p.y = bf2f((unsigned short)(pk[jt].x >> 16))    * invd;
                    p.z = bf2f((unsigned short)(pk[jt].y & 0xFFFF)) * invd;
                    p.w = bf2f((unsigned short)(pk[jt].y >> 16))    * invd;
                    __builtin_nontemporal_store(p, (f32x4*)(srow + jt * 16 + g * 4));
                }
            }
        }

        // ---- PV: D[d][l] = sum_j V^T[d][j] P[l][j]; B-frags via shuffles --
        {
            f32x4 acc[4] = {{0.f,0.f,0.f,0.f},{0.f,0.f,0.f,0.f},
                            {0.f,0.f,0.f,0.f},{0.f,0.f,0.f,0.f}};
            const int src = lr + ((g & 1) << 5);
#pragma unroll
            for (int jt32 = 0; jt32 < 4; ++jt32) {
                uint2 sel;
                if (jt32 < 3) {
                    sel = (g & 2) ? pk[jt32 * 2 + 1] : pk[jt32 * 2];
                } else {  // pk[7] doesn't exist; those j>=112 are all zero
                    uint2 z; z.x = 0; z.y = 0;
                    sel = (g & 2) ? z : pk[6];
                }
                unsigned b0 = (unsigned)__shfl((int)sel.x, src, 64);
                unsigned b1 = (unsigned)__shfl((int)sel.y, src, 64);
                unsigned b2 = (unsigned)__shfl((int)sel.x, src + 16, 64);
                unsigned b3 = (unsigned)__shfl((int)sel.y, src + 16, 64);
                union { unsigned u[4]; short8b s; } bb;
                bb.u[0] = b0; bb.u[1] = b1; bb.u[2] = b2; bb.u[3] = b3;
                const int j0 = (jt32 == 3) ? 96 : (jt32 * 32 + g * 8);
#pragma unroll
                for (int dt = 0; dt < 4; ++dt) {
                    const char* ap = smem + VT + (dt * 16 + lr) * 240 + j0 * 2;
                    short8b Av = *(const short8b*)ap;
                    acc[dt] = __builtin_amdgcn_mfma_f32_16x16x32_bf16(Av, bb.s, acc[dt], 0, 0, 0);
                }
            }
            if (l < 100) {
#pragma unroll
                for (int dt = 0; dt < 4; ++dt) {
                    f32x4 o = acc[dt];
                    o.x *= invd; o.y *= invd; o.z *= invd; o.w *= invd;
                    __builtin_nontemporal_store(
                        o, (f32x4*)(Vout + ((size_t)(b * L_ + l) * H_ + h) * D_ + dt * 16 + g * 4));
                }
            }
        }
    }

    // ---- prior + sig tail: this block covers half of the (b,h) tile ----
    {
        const size_t base4 = (size_t)bh * 2500;
        const float4* d4 = (const float4*)dist;
        f32x4* p4 = (f32x4*)prior;
        f32x4* s4 = (f32x4*)sigout;
        const int lo = half * 1250, hi = lo + 1250;
        for (int idx = lo + t; idx < hi; idx += 256) {
            int lrow = idx / 25;
            float x = sigma[((size_t)b * L_ + lrow) * H_ + h];
            float s = 1.0f / (1.0f + exp2f(-5.0f * LOG2E * x)) + 1e-5f;
            float sg = expm1f(s * LN3);   // 3^s - 1, accurate near 0
            float inv = 1.0f / sg;
            float c1 = INV_SQRT_2PI * inv;
            float c2 = 0.5f * LOG2E * inv * inv;
            float4 d = d4[idx];
            f32x4 pr;
            pr.x = c1 * exp2f(-d.x * d.x * c2);
            pr.y = c1 * exp2f(-d.y * d.y * c2);
            pr.z = c1 * exp2f(-d.z * d.z * c2);
            pr.w = c1 * exp2f(-d.w * d.w * c2);
            f32x4 sv = {sg, sg, sg, sg};
            __builtin_nontemporal_store(pr, p4 + base4 + idx);
            __builtin_nontemporal_store(sv, s4 + base4 + idx);
        }
    }
}

extern "C" void kernel_launch(void* const* d_in, const int* in_sizes, int n_in,
                              void* d_out, int out_size, void* d_ws, size_t ws_size,
                              hipStream_t stream) {
    const float* Q     = (const float*)d_in[0];
    const float* K     = (const float*)d_in[1];
    const float* V     = (const float*)d_in[2];
    const float* sigma = (const float*)d_in[3];
    const float* dist  = (const float*)d_in[4];

    float* out    = (float*)d_out;
    float* Vout   = out;
    float* series = out + OFF_SERIES;
    float* prior  = out + OFF_PRIOR;
    float* sigout = out + OFF_SIG;
    float* Mout   = out + OFF_M;

    hipLaunchKernelGGL(fused_kernel, dim3(2 * B_ * H_), dim3(256), 0, stream,
                       Q, K, V, sigma, dist, Vout, series, prior, sigout, Mout);
}

// Round 12
// 118.506 us; speedup vs baseline: 3.3266x; 1.0262x over previous
//
#include <hip/hip_runtime.h>
#include <math.h>

#define B_ 256
#define L_ 100
#define H_ 8
#define E_ 64
#define D_ 64

// Output offsets (floats): V[B,L,H,D], series[B,H,L,L], prior, sig, M[B,H,L]
#define OFF_SERIES ((size_t)B_ * L_ * H_ * D_)
#define OFF_PRIOR  (OFF_SERIES + (size_t)B_ * H_ * L_ * L_)
#define OFF_SIG    (OFF_PRIOR  + (size_t)B_ * H_ * L_ * L_)
#define OFF_M      (OFF_SIG    + (size_t)B_ * H_ * L_ * L_)

#define LOG2E 1.4426950408889634f
#define LN3   1.0986122886681098f
#define INV_SQRT_2PI 0.3989422804014327f

typedef __attribute__((ext_vector_type(8))) short short8b;  // 8 bf16
typedef __attribute__((ext_vector_type(4))) float f32x4;

// LDS layout (bytes)
#define KHI 0        // K hi bf16 [100][64], 128B rows, XOR swizzle: 12800
#define KLO 12800    // K lo bf16: 12800
#define VT  25600    // V^T bf16 [64 d][120 j] (240B rows, 16B-aligned): 15360
#define SMEM_BYTES 40960   // 40 KB -> 4 blocks/CU (LDS-wise)

__device__ __forceinline__ void cvt_split8(const float* f, short8b& hi, short8b& lo) {
#pragma unroll
    for (int i = 0; i < 8; ++i) {
        unsigned u = __float_as_uint(f[i]);
        hi[i] = (short)(u >> 16);
        float r = f[i] - __uint_as_float(u & 0xFFFF0000u);
        lo[i] = (short)(__float_as_uint(r) >> 16);
    }
}
__device__ __forceinline__ unsigned short f2bf_rn(float x) {  // round-to-nearest-even
    unsigned u = __float_as_uint(x);
    return (unsigned short)((u + 0x7FFFu + ((u >> 16) & 1u)) >> 16);
}
__device__ __forceinline__ float bf2f(unsigned short v) {
    return __uint_as_float((unsigned)v << 16);
}

// Fused kernel, grid = 2*B*H. XCD pair-swizzle: the two half-blocks of one
// (b,h) get dispatch indices 8 apart -> same XCD (bid%8) -> the second one's
// K/V reads hit that XCD's L2. NT stores for all outputs (write-only).
// __launch_bounds__(256,4): force VGPR<=128 (was 132) -> 4 waves/SIMD
// instead of 2-3 (occupancy halves at the 128-VGPR step, m69).
__global__ __launch_bounds__(256, 4) void fused_kernel(
    const float* __restrict__ Q, const float* __restrict__ K,
    const float* __restrict__ Vin, const float* __restrict__ sigma,
    const float* __restrict__ dist, float* __restrict__ Vout,
    float* __restrict__ series, float* __restrict__ prior,
    float* __restrict__ sigout, float* __restrict__ Mout) {
    const int bid = blockIdx.x;
    const int grp = bid >> 4;                 // 16 consecutive bids = 8 bh x 2 halves
    const int bh   = grp * 8 + (bid & 7);     // halves sit 8 apart -> same bid%8
    const int half = (bid >> 3) & 1;
    const int b = bh >> 3, h = bh & 7;
    __shared__ __align__(16) char smem[SMEM_BYTES];
    const int t = threadIdx.x;

    // ---- stage K as split-bf16 hi/lo (row XOR-swizzle, R4-proven) ----
    for (int ci = t; ci < 800; ci += 256) {
        int row = ci >> 3, c8 = ci & 7;
        const float* src = K + ((size_t)(b * L_ + row) * H_ + h) * E_ + c8 * 8;
        float4 f0 = *(const float4*)src;
        float4 f1 = *(const float4*)(src + 4);
        float f[8] = {f0.x, f0.y, f0.z, f0.w, f1.x, f1.y, f1.z, f1.w};
        short8b hi8, lo8;
        cvt_split8(f, hi8, lo8);
        int byte = (row * 128 + c8 * 16) ^ ((row & 7) << 4);
        *(short8b*)(smem + KHI + byte) = hi8;
        *(short8b*)(smem + KLO + byte) = lo8;
    }
    // ---- stage V^T bf16 [64][120], two j-columns per u32 write ----
    for (int f = t; f < 800; f += 256) {
        int j2 = f >> 4, c = f & 15;   // j2: 0..49, c: 0..15
        const float* vp = Vin + ((size_t)(b * L_ + 2 * j2) * H_ + h) * D_ + c * 4;
        float4 v0 = *(const float4*)vp;
        float4 v1 = *(const float4*)(vp + H_ * D_);
        float a0[4] = {v0.x, v0.y, v0.z, v0.w};
        float a1[4] = {v1.x, v1.y, v1.z, v1.w};
#pragma unroll
        for (int i = 0; i < 4; ++i) {
            unsigned pkd = (unsigned)f2bf_rn(a0[i]) | ((unsigned)f2bf_rn(a1[i]) << 16);
            *(unsigned*)(smem + VT + (c * 4 + i) * 240 + j2 * 4) = pkd;
        }
    }
    if (t < 64) {   // zero cols 100..105 (k-tail reads cover <=103)
        *(unsigned*)(smem + VT + t * 240 + 200) = 0;
        *(unsigned*)(smem + VT + t * 240 + 204) = 0;
        *(unsigned*)(smem + VT + t * 240 + 208) = 0;
    }

    const int wave = t >> 6;
    const int lane = t & 63;
    const int lr = lane & 15;   // l-offset in tile (MFMA col)
    const int g  = lane >> 4;   // k-group
    const int lt = half * 4 + wave;
    const bool active = (lt < 7);
    const int l = lt * 16 + lr;

    // ---- Q B-frags from global (VMEM, no LDS dep) + register split ----
    short8b qh[2], ql[2];
    if (active) {
        const int lrow = (l < 100) ? l : 99;
        const float* qp = Q + ((size_t)(b * L_ + lrow) * H_ + h) * E_;
#pragma unroll
        for (int es = 0; es < 2; ++es) {
            float4 f0 = *(const float4*)(qp + es * 32 + g * 8);
            float4 f1 = *(const float4*)(qp + es * 32 + g * 8 + 4);
            float f[8] = {f0.x, f0.y, f0.z, f0.w, f1.x, f1.y, f1.z, f1.w};
            cvt_split8(f, qh[es], ql[es]);
        }
    }
    __syncthreads();

    if (active) {
        const float cs = 0.125f * LOG2E;
        float m1 = -INFINITY, m2 = -INFINITY, sum1 = 0.f, sum2 = 0.f, den = 0.f;
        uint2 pk[7];
#pragma unroll
        for (int jt = 0; jt < 7; ++jt) {
            int jrow = jt * 16 + lr; if (jrow > 99) jrow = 99;
            int rb = jrow * 128, sw = (jrow & 7) << 4;
            f32x4 C = {0.f, 0.f, 0.f, 0.f};
#pragma unroll
            for (int es = 0; es < 2; ++es) {
                int byte = (rb + g * 16 + es * 64) ^ sw;
                short8b kh = *(const short8b*)(smem + KHI + byte);
                short8b kl = *(const short8b*)(smem + KLO + byte);
                C = __builtin_amdgcn_mfma_f32_16x16x32_bf16(kh, qh[es], C, 0, 0, 0);
                C = __builtin_amdgcn_mfma_f32_16x16x32_bf16(kh, ql[es], C, 0, 0, 0);
                C = __builtin_amdgcn_mfma_f32_16x16x32_bf16(kl, qh[es], C, 0, 0, 0);
            }
            unsigned short pw[4] = {0, 0, 0, 0};
#pragma unroll
            for (int r = 0; r < 4; ++r) {
                int j = jt * 16 + g * 4 + r;
                float s = C[r];
                if (j < 100) {
                    m1 = fmaxf(m1, s);
                    sum1 += s;
                    bool band = (j - l < 3) && (l - j < 3);
                    float sp = band ? 0.f : s;
                    m2 = fmaxf(m2, sp);
                    sum2 += sp;
                    float p = exp2f(s * cs);
                    den += p;                           // diag included in den
                    pw[r] = (j == l) ? 0 : f2bf_rn(p);  // diag zeroed in output
                }
            }
            pk[jt].x = (unsigned)pw[0] | ((unsigned)pw[1] << 16);
            pk[jt].y = (unsigned)pw[2] | ((unsigned)pw[3] << 16);
        }
        // combine the 4 k-groups -> every lane holds full stats for its lr
        m1   = fmaxf(m1, __shfl_xor(m1, 16, 64));
        m1   = fmaxf(m1, __shfl_xor(m1, 32, 64));
        m2   = fmaxf(m2, __shfl_xor(m2, 16, 64));
        m2   = fmaxf(m2, __shfl_xor(m2, 32, 64));
        sum1 += __shfl_xor(sum1, 16, 64);
        sum1 += __shfl_xor(sum1, 32, 64);
        sum2 += __shfl_xor(sum2, 16, 64);
        sum2 += __shfl_xor(sum2, 32, 64);
        den  += __shfl_xor(den, 16, 64);
        den  += __shfl_xor(den, 32, 64);
        const float invd = 1.0f / den;

        if (lane < 16 && l < 100) {
            float M1 = m1 - sum1 * (1.0f / 100.0f);
            float M2 = m2 - sum2 * (1.0f / 94.0f);
            __builtin_nontemporal_store(M1 - M2, Mout + (size_t)bh * L_ + l);
        }
        if (l < 100) {
            float* srow = series + ((size_t)bh * L_ + l) * L_;
#pragma unroll
            for (int jt = 0; jt < 7; ++jt) {
                if (jt < 6 || g == 0) {
                    f32x4 p;
                    p.x = bf2f((unsigned short)(pk[jt].x & 0xFFFF)) * invd;
                    p.y = bf2f((unsigned short)(pk[jt].x >> 16))    * invd;
                    p.z = bf2f((unsigned short)(pk[jt].y & 0xFFFF)) * invd;
                    p.w = bf2f((unsigned short)(pk[jt].y >> 16))    * invd;
                    __builtin_nontemporal_store(p, (f32x4*)(srow + jt * 16 + g * 4));
                }
            }
        }

        // ---- PV: D[d][l] = sum_j V^T[d][j] P[l][j]; B-frags via shuffles --
        {
            f32x4 acc[4] = {{0.f,0.f,0.f,0.f},{0.f,0.f,0.f,0.f},
                            {0.f,0.f,0.f,0.f},{0.f,0.f,0.f,0.f}};
            const int src = lr + ((g & 1) << 5);
#pragma unroll
            for (int jt32 = 0; jt32 < 4; ++jt32) {
                uint2 sel;
                if (jt32 < 3) {
                    sel = (g & 2) ? pk[jt32 * 2 + 1] : pk[jt32 * 2];
                } else {  // pk[7] doesn't exist; those j>=112 are all zero
                    uint2 z; z.x = 0; z.y = 0;
                    sel = (g & 2) ? z : pk[6];
                }
                unsigned b0 = (unsigned)__shfl((int)sel.x, src, 64);
                unsigned b1 = (unsigned)__shfl((int)sel.y, src, 64);
                unsigned b2 = (unsigned)__shfl((int)sel.x, src + 16, 64);
                unsigned b3 = (unsigned)__shfl((int)sel.y, src + 16, 64);
                union { unsigned u[4]; short8b s; } bb;
                bb.u[0] = b0; bb.u[1] = b1; bb.u[2] = b2; bb.u[3] = b3;
                const int j0 = (jt32 == 3) ? 96 : (jt32 * 32 + g * 8);
#pragma unroll
                for (int dt = 0; dt < 4; ++dt) {
                    const char* ap = smem + VT + (dt * 16 + lr) * 240 + j0 * 2;
                    short8b Av = *(const short8b*)ap;
                    acc[dt] = __builtin_amdgcn_mfma_f32_16x16x32_bf16(Av, bb.s, acc[dt], 0, 0, 0);
                }
            }
            if (l < 100) {
#pragma unroll
                for (int dt = 0; dt < 4; ++dt) {
                    f32x4 o = acc[dt];
                    o.x *= invd; o.y *= invd; o.z *= invd; o.w *= invd;
                    __builtin_nontemporal_store(
                        o, (f32x4*)(Vout + ((size_t)(b * L_ + l) * H_ + h) * D_ + dt * 16 + g * 4));
                }
            }
        }
    }

    // ---- prior + sig tail: this block covers half of the (b,h) tile ----
    {
        const size_t base4 = (size_t)bh * 2500;
        const float4* d4 = (const float4*)dist;
        f32x4* p4 = (f32x4*)prior;
        f32x4* s4 = (f32x4*)sigout;
        const int lo = half * 1250, hi = lo + 1250;
        for (int idx = lo + t; idx < hi; idx += 256) {
            int lrow = idx / 25;
            float x = sigma[((size_t)b * L_ + lrow) * H_ + h];
            float s = 1.0f / (1.0f + exp2f(-5.0f * LOG2E * x)) + 1e-5f;
            float sg = expm1f(s * LN3);   // 3^s - 1, accurate near 0
            float inv = 1.0f / sg;
            float c1 = INV_SQRT_2PI * inv;
            float c2 = 0.5f * LOG2E * inv * inv;
            float4 d = d4[idx];
            f32x4 pr;
            pr.x = c1 * exp2f(-d.x * d.x * c2);
            pr.y = c1 * exp2f(-d.y * d.y * c2);
            pr.z = c1 * exp2f(-d.z * d.z * c2);
            pr.w = c1 * exp2f(-d.w * d.w * c2);
            f32x4 sv = {sg, sg, sg, sg};
            __builtin_nontemporal_store(pr, p4 + base4 + idx);
            __builtin_nontemporal_store(sv, s4 + base4 + idx);
        }
    }
}

extern "C" void kernel_launch(void* const* d_in, const int* in_sizes, int n_in,
                              void* d_out, int out_size, void* d_ws, size_t ws_size,
                              hipStream_t stream) {
    const float* Q     = (const float*)d_in[0];
    const float* K     = (const float*)d_in[1];
    const float* V     = (const float*)d_in[2];
    const float* sigma = (const float*)d_in[3];
    const float* dist  = (const float*)d_in[4];

    float* out    = (float*)d_out;
    float* Vout   = out;
    float* series = out + OFF_SERIES;
    float* prior  = out + OFF_PRIOR;
    float* sigout = out + OFF_SIG;
    float* Mout   = out + OFF_M;

    hipLaunchKernelGGL(fused_kernel, dim3(2 * B_ * H_), dim3(256), 0, stream,
                       Q, K, V, sigma, dist, Vout, series, prior, sigout, Mout);
}

// Round 13
// 110.644 us; speedup vs baseline: 3.5629x; 1.0711x over previous
//
#include <hip/hip_runtime.h>
#include <math.h>

#define B_ 256
#define L_ 100
#define H_ 8
#define E_ 64
#define D_ 64

// Output offsets (floats): V[B,L,H,D], series[B,H,L,L], prior, sig, M[B,H,L]
#define OFF_SERIES ((size_t)B_ * L_ * H_ * D_)
#define OFF_PRIOR  (OFF_SERIES + (size_t)B_ * H_ * L_ * L_)
#define OFF_SIG    (OFF_PRIOR  + (size_t)B_ * H_ * L_ * L_)
#define OFF_M      (OFF_SIG    + (size_t)B_ * H_ * L_ * L_)

#define LOG2E 1.4426950408889634f
#define LN3   1.0986122886681098f
#define INV_SQRT_2PI 0.3989422804014327f

typedef __attribute__((ext_vector_type(8))) short short8b;  // 8 bf16
typedef __attribute__((ext_vector_type(4))) float f32x4;

// LDS layout (bytes)
#define KHI 0        // K hi bf16 [100][64], 128B rows, XOR swizzle: 12800
#define KLO 12800    // K lo bf16: 12800
#define VT  25600    // V^T bf16 [64 d][120 j] (240B rows, 16B-aligned): 15360
#define SMEM_BYTES 40960   // 40 KB

__device__ __forceinline__ void cvt_split8(const float* f, short8b& hi, short8b& lo) {
#pragma unroll
    for (int i = 0; i < 8; ++i) {
        unsigned u = __float_as_uint(f[i]);
        hi[i] = (short)(u >> 16);
        float r = f[i] - __uint_as_float(u & 0xFFFF0000u);
        lo[i] = (short)(__float_as_uint(r) >> 16);
    }
}
__device__ __forceinline__ unsigned short f2bf_rn(float x) {  // round-to-nearest-even
    unsigned u = __float_as_uint(x);
    return (unsigned short)((u + 0x7FFFu + ((u >> 16) & 1u)) >> 16);
}
__device__ __forceinline__ float bf2f(unsigned short v) {
    return __uint_as_float((unsigned)v << 16);
}

// One 512-thread block per (b,h): K/V staged ONCE (R12 staged twice via two
// half-blocks -> 105 MB duplicate HBM fetch). Waves 0-6 own one l-tile each
// (R12-proven per-wave path); wave 7 helps staging + prior tail only.
// 128 VGPR -> 4 waves/SIMD -> 2 blocks/CU; NT stores for all outputs.
__global__ __launch_bounds__(512, 4) void fused_kernel(
    const float* __restrict__ Q, const float* __restrict__ K,
    const float* __restrict__ Vin, const float* __restrict__ sigma,
    const float* __restrict__ dist, float* __restrict__ Vout,
    float* __restrict__ series, float* __restrict__ prior,
    float* __restrict__ sigout, float* __restrict__ Mout) {
    const int bh = blockIdx.x;
    const int b = bh >> 3, h = bh & 7;
    __shared__ __align__(16) char smem[SMEM_BYTES];
    const int t = threadIdx.x;

    // ---- stage K as split-bf16 hi/lo (row XOR-swizzle, R4-proven) ----
    for (int ci = t; ci < 800; ci += 512) {
        int row = ci >> 3, c8 = ci & 7;
        const float* src = K + ((size_t)(b * L_ + row) * H_ + h) * E_ + c8 * 8;
        float4 f0 = *(const float4*)src;
        float4 f1 = *(const float4*)(src + 4);
        float f[8] = {f0.x, f0.y, f0.z, f0.w, f1.x, f1.y, f1.z, f1.w};
        short8b hi8, lo8;
        cvt_split8(f, hi8, lo8);
        int byte = (row * 128 + c8 * 16) ^ ((row & 7) << 4);
        *(short8b*)(smem + KHI + byte) = hi8;
        *(short8b*)(smem + KLO + byte) = lo8;
    }
    // ---- stage V^T bf16 [64][120], two j-columns per u32 write ----
    for (int f = t; f < 800; f += 512) {
        int j2 = f >> 4, c = f & 15;   // j2: 0..49, c: 0..15
        const float* vp = Vin + ((size_t)(b * L_ + 2 * j2) * H_ + h) * D_ + c * 4;
        float4 v0 = *(const float4*)vp;
        float4 v1 = *(const float4*)(vp + H_ * D_);
        float a0[4] = {v0.x, v0.y, v0.z, v0.w};
        float a1[4] = {v1.x, v1.y, v1.z, v1.w};
#pragma unroll
        for (int i = 0; i < 4; ++i) {
            unsigned pkd = (unsigned)f2bf_rn(a0[i]) | ((unsigned)f2bf_rn(a1[i]) << 16);
            *(unsigned*)(smem + VT + (c * 4 + i) * 240 + j2 * 4) = pkd;
        }
    }
    if (t < 64) {   // zero cols 100..105 (k-tail reads cover <=103)
        *(unsigned*)(smem + VT + t * 240 + 200) = 0;
        *(unsigned*)(smem + VT + t * 240 + 204) = 0;
        *(unsigned*)(smem + VT + t * 240 + 208) = 0;
    }

    const int wave = t >> 6;
    const int lane = t & 63;
    const int lr = lane & 15;   // l-offset in tile (MFMA col)
    const int g  = lane >> 4;   // k-group
    const int lt = wave;        // one l-tile per wave; wave 7 inactive
    const bool active = (lt < 7);
    const int l = lt * 16 + lr;

    // ---- Q B-frags from global (VMEM, no LDS dep) + register split ----
    short8b qh[2], ql[2];
    if (active) {
        const int lrow = (l < 100) ? l : 99;
        const float* qp = Q + ((size_t)(b * L_ + lrow) * H_ + h) * E_;
#pragma unroll
        for (int es = 0; es < 2; ++es) {
            float4 f0 = *(const float4*)(qp + es * 32 + g * 8);
            float4 f1 = *(const float4*)(qp + es * 32 + g * 8 + 4);
            float f[8] = {f0.x, f0.y, f0.z, f0.w, f1.x, f1.y, f1.z, f1.w};
            cvt_split8(f, qh[es], ql[es]);
        }
    }
    __syncthreads();

    if (active) {
        const float cs = 0.125f * LOG2E;
        float m1 = -INFINITY, m2 = -INFINITY, sum1 = 0.f, sum2 = 0.f, den = 0.f;
        uint2 pk[7];
#pragma unroll
        for (int jt = 0; jt < 7; ++jt) {
            int jrow = jt * 16 + lr; if (jrow > 99) jrow = 99;
            int rb = jrow * 128, sw = (jrow & 7) << 4;
            f32x4 C = {0.f, 0.f, 0.f, 0.f};
#pragma unroll
            for (int es = 0; es < 2; ++es) {
                int byte = (rb + g * 16 + es * 64) ^ sw;
                short8b kh = *(const short8b*)(smem + KHI + byte);
                short8b kl = *(const short8b*)(smem + KLO + byte);
                C = __builtin_amdgcn_mfma_f32_16x16x32_bf16(kh, qh[es], C, 0, 0, 0);
                C = __builtin_amdgcn_mfma_f32_16x16x32_bf16(kh, ql[es], C, 0, 0, 0);
                C = __builtin_amdgcn_mfma_f32_16x16x32_bf16(kl, qh[es], C, 0, 0, 0);
            }
            unsigned short pw[4] = {0, 0, 0, 0};
#pragma unroll
            for (int r = 0; r < 4; ++r) {
                int j = jt * 16 + g * 4 + r;
                float s = C[r];
                if (j < 100) {
                    m1 = fmaxf(m1, s);
                    sum1 += s;
                    bool band = (j - l < 3) && (l - j < 3);
                    float sp = band ? 0.f : s;
                    m2 = fmaxf(m2, sp);
                    sum2 += sp;
                    float p = exp2f(s * cs);
                    den += p;                           // diag included in den
                    pw[r] = (j == l) ? 0 : f2bf_rn(p);  // diag zeroed in output
                }
            }
            pk[jt].x = (unsigned)pw[0] | ((unsigned)pw[1] << 16);
            pk[jt].y = (unsigned)pw[2] | ((unsigned)pw[3] << 16);
        }
        // combine the 4 k-groups -> every lane holds full stats for its lr
        m1   = fmaxf(m1, __shfl_xor(m1, 16, 64));
        m1   = fmaxf(m1, __shfl_xor(m1, 32, 64));
        m2   = fmaxf(m2, __shfl_xor(m2, 16, 64));
        m2   = fmaxf(m2, __shfl_xor(m2, 32, 64));
        sum1 += __shfl_xor(sum1, 16, 64);
        sum1 += __shfl_xor(sum1, 32, 64);
        sum2 += __shfl_xor(sum2, 16, 64);
        sum2 += __shfl_xor(sum2, 32, 64);
        den  += __shfl_xor(den, 16, 64);
        den  += __shfl_xor(den, 32, 64);
        const float invd = 1.0f / den;

        if (lane < 16 && l < 100) {
            float M1 = m1 - sum1 * (1.0f / 100.0f);
            float M2 = m2 - sum2 * (1.0f / 94.0f);
            __builtin_nontemporal_store(M1 - M2, Mout + (size_t)bh * L_ + l);
        }
        if (l < 100) {
            float* srow = series + ((size_t)bh * L_ + l) * L_;
#pragma unroll
            for (int jt = 0; jt < 7; ++jt) {
                if (jt < 6 || g == 0) {
                    f32x4 p;
                    p.x = bf2f((unsigned short)(pk[jt].x & 0xFFFF)) * invd;
                    p.y = bf2f((unsigned short)(pk[jt].x >> 16))    * invd;
                    p.z = bf2f((unsigned short)(pk[jt].y & 0xFFFF)) * invd;
                    p.w = bf2f((unsigned short)(pk[jt].y >> 16))    * invd;
                    __builtin_nontemporal_store(p, (f32x4*)(srow + jt * 16 + g * 4));
                }
            }
        }

        // ---- PV: D[d][l] = sum_j V^T[d][j] P[l][j]; B-frags via shuffles --
        {
            f32x4 acc[4] = {{0.f,0.f,0.f,0.f},{0.f,0.f,0.f,0.f},
                            {0.f,0.f,0.f,0.f},{0.f,0.f,0.f,0.f}};
            const int src = lr + ((g & 1) << 5);
#pragma unroll
            for (int jt32 = 0; jt32 < 4; ++jt32) {
                uint2 sel;
                if (jt32 < 3) {
                    sel = (g & 2) ? pk[jt32 * 2 + 1] : pk[jt32 * 2];
                } else {  // pk[7] doesn't exist; those j>=112 are all zero
                    uint2 z; z.x = 0; z.y = 0;
                    sel = (g & 2) ? z : pk[6];
                }
                unsigned b0 = (unsigned)__shfl((int)sel.x, src, 64);
                unsigned b1 = (unsigned)__shfl((int)sel.y, src, 64);
                unsigned b2 = (unsigned)__shfl((int)sel.x, src + 16, 64);
                unsigned b3 = (unsigned)__shfl((int)sel.y, src + 16, 64);
                union { unsigned u[4]; short8b s; } bb;
                bb.u[0] = b0; bb.u[1] = b1; bb.u[2] = b2; bb.u[3] = b3;
                const int j0 = (jt32 == 3) ? 96 : (jt32 * 32 + g * 8);
#pragma unroll
                for (int dt = 0; dt < 4; ++dt) {
                    const char* ap = smem + VT + (dt * 16 + lr) * 240 + j0 * 2;
                    short8b Av = *(const short8b*)ap;
                    acc[dt] = __builtin_amdgcn_mfma_f32_16x16x32_bf16(Av, bb.s, acc[dt], 0, 0, 0);
                }
            }
            if (l < 100) {
#pragma unroll
                for (int dt = 0; dt < 4; ++dt) {
                    f32x4 o = acc[dt];
                    o.x *= invd; o.y *= invd; o.z *= invd; o.w *= invd;
                    __builtin_nontemporal_store(
                        o, (f32x4*)(Vout + ((size_t)(b * L_ + l) * H_ + h) * D_ + dt * 16 + g * 4));
                }
            }
        }
    }

    // ---- prior + sig tail: whole (b,h) tile, all 8 waves ----
    {
        const size_t base4 = (size_t)bh * 2500;
        const float4* d4 = (const float4*)dist;
        f32x4* p4 = (f32x4*)prior;
        f32x4* s4 = (f32x4*)sigout;
        for (int idx = t; idx < 2500; idx += 512) {
            int lrow = idx / 25;
            float x = sigma[((size_t)b * L_ + lrow) * H_ + h];
            float s = 1.0f / (1.0f + exp2f(-5.0f * LOG2E * x)) + 1e-5f;
            float sg = expm1f(s * LN3);   // 3^s - 1, accurate near 0
            float inv = 1.0f / sg;
            float c1 = INV_SQRT_2PI * inv;
            float c2 = 0.5f * LOG2E * inv * inv;
            float4 d = d4[idx];
            f32x4 pr;
            pr.x = c1 * exp2f(-d.x * d.x * c2);
            pr.y = c1 * exp2f(-d.y * d.y * c2);
            pr.z = c1 * exp2f(-d.z * d.z * c2);
            pr.w = c1 * exp2f(-d.w * d.w * c2);
            f32x4 sv = {sg, sg, sg, sg};
            __builtin_nontemporal_store(pr, p4 + base4 + idx);
            __builtin_nontemporal_store(sv, s4 + base4 + idx);
        }
    }
}

extern "C" void kernel_launch(void* const* d_in, const int* in_sizes, int n_in,
                              void* d_out, int out_size, void* d_ws, size_t ws_size,
                              hipStream_t stream) {
    const float* Q     = (const float*)d_in[0];
    const float* K     = (const float*)d_in[1];
    const float* V     = (const float*)d_in[2];
    const float* sigma = (const float*)d_in[3];
    const float* dist  = (const float*)d_in[4];

    float* out    = (float*)d_out;
    float* Vout   = out;
    float* series = out + OFF_SERIES;
    float* prior  = out + OFF_PRIOR;
    float* sigout = out + OFF_SIG;
    float* Mout   = out + OFF_M;

    hipLaunchKernelGGL(fused_kernel, dim3(B_ * H_), dim3(512), 0, stream,
                       Q, K, V, sigma, dist, Vout, series, prior, sigout, Mout);
}

// Round 14
// 107.790 us; speedup vs baseline: 3.6573x; 1.0265x over previous
//
#include <hip/hip_runtime.h>
#include <math.h>

#define B_ 256
#define L_ 100
#define H_ 8
#define E_ 64
#define D_ 64

// Output offsets (floats): V[B,L,H,D], series[B,H,L,L], prior, sig, M[B,H,L]
#define OFF_SERIES ((size_t)B_ * L_ * H_ * D_)
#define OFF_PRIOR  (OFF_SERIES + (size_t)B_ * H_ * L_ * L_)
#define OFF_SIG    (OFF_PRIOR  + (size_t)B_ * H_ * L_ * L_)
#define OFF_M      (OFF_SIG    + (size_t)B_ * H_ * L_ * L_)

#define LOG2E 1.4426950408889634f
#define LN3   1.0986122886681098f
#define INV_SQRT_2PI 0.3989422804014327f

typedef __attribute__((ext_vector_type(8))) short short8b;  // 8 bf16
typedef __attribute__((ext_vector_type(4))) float f32x4;

// LDS layout (bytes)
#define KHI 0        // K hi bf16 [100][64], 128B rows, XOR swizzle: 12800
#define KLO 12800    // K lo bf16: 12800
#define VT  25600    // V^T bf16 [64 d][120 j] (240B rows, 16B-aligned): 15360
#define SGC 40960    // sigma constants: sgs[100], c1s[100], c2s[100] f32
#define SMEM_BYTES 42240

__device__ __forceinline__ void cvt_split8(const float* f, short8b& hi, short8b& lo) {
#pragma unroll
    for (int i = 0; i < 8; ++i) {
        unsigned u = __float_as_uint(f[i]);
        hi[i] = (short)(u >> 16);
        float r = f[i] - __uint_as_float(u & 0xFFFF0000u);
        lo[i] = (short)(__float_as_uint(r) >> 16);
    }
}
__device__ __forceinline__ unsigned short f2bf_rn(float x) {  // round-to-nearest-even
    unsigned u = __float_as_uint(x);
    return (unsigned short)((u + 0x7FFFu + ((u >> 16) & 1u)) >> 16);
}
__device__ __forceinline__ float bf2f(unsigned short v) {
    return __uint_as_float((unsigned)v << 16);
}

// One 512-thread block per (b,h); K/V staged once; waves 0-6 one l-tile each.
// R14 changes vs R13: (1) NT only on the fully-coalesced prior/sig streams
// (series/Vout write 64B segments -> let L2 combine them into full lines);
// (2) sigma-derived constants precomputed once into LDS (tail read broadcast,
// kills the 25x-redundant sigmoid/expm1/rcp chain).
__global__ __launch_bounds__(512, 4) void fused_kernel(
    const float* __restrict__ Q, const float* __restrict__ K,
    const float* __restrict__ Vin, const float* __restrict__ sigma,
    const float* __restrict__ dist, float* __restrict__ Vout,
    float* __restrict__ series, float* __restrict__ prior,
    float* __restrict__ sigout, float* __restrict__ Mout) {
    const int bh = blockIdx.x;
    const int b = bh >> 3, h = bh & 7;
    __shared__ __align__(16) char smem[SMEM_BYTES];
    float* sgs = (float*)(smem + SGC);
    float* c1s = sgs + 100;
    float* c2s = sgs + 200;
    const int t = threadIdx.x;

    // ---- stage K as split-bf16 hi/lo (row XOR-swizzle, R4-proven) ----
    for (int ci = t; ci < 800; ci += 512) {
        int row = ci >> 3, c8 = ci & 7;
        const float* src = K + ((size_t)(b * L_ + row) * H_ + h) * E_ + c8 * 8;
        float4 f0 = *(const float4*)src;
        float4 f1 = *(const float4*)(src + 4);
        float f[8] = {f0.x, f0.y, f0.z, f0.w, f1.x, f1.y, f1.z, f1.w};
        short8b hi8, lo8;
        cvt_split8(f, hi8, lo8);
        int byte = (row * 128 + c8 * 16) ^ ((row & 7) << 4);
        *(short8b*)(smem + KHI + byte) = hi8;
        *(short8b*)(smem + KLO + byte) = lo8;
    }
    // ---- stage V^T bf16 [64][120], two j-columns per u32 write ----
    for (int f = t; f < 800; f += 512) {
        int j2 = f >> 4, c = f & 15;   // j2: 0..49, c: 0..15
        const float* vp = Vin + ((size_t)(b * L_ + 2 * j2) * H_ + h) * D_ + c * 4;
        float4 v0 = *(const float4*)vp;
        float4 v1 = *(const float4*)(vp + H_ * D_);
        float a0[4] = {v0.x, v0.y, v0.z, v0.w};
        float a1[4] = {v1.x, v1.y, v1.z, v1.w};
#pragma unroll
        for (int i = 0; i < 4; ++i) {
            unsigned pkd = (unsigned)f2bf_rn(a0[i]) | ((unsigned)f2bf_rn(a1[i]) << 16);
            *(unsigned*)(smem + VT + (c * 4 + i) * 240 + j2 * 4) = pkd;
        }
    }
    if (t < 64) {   // zero cols 100..105 (k-tail reads cover <=103)
        *(unsigned*)(smem + VT + t * 240 + 200) = 0;
        *(unsigned*)(smem + VT + t * 240 + 204) = 0;
        *(unsigned*)(smem + VT + t * 240 + 208) = 0;
    }
    if (t < 100) {  // sigma-derived per-row constants, once per block
        float x = sigma[((size_t)b * L_ + t) * H_ + h];
        float s = 1.0f / (1.0f + exp2f(-5.0f * LOG2E * x)) + 1e-5f;
        float sg = expm1f(s * LN3);   // 3^s - 1, accurate near 0
        float inv = 1.0f / sg;
        sgs[t] = sg;
        c1s[t] = INV_SQRT_2PI * inv;
        c2s[t] = 0.5f * LOG2E * inv * inv;
    }

    const int wave = t >> 6;
    const int lane = t & 63;
    const int lr = lane & 15;   // l-offset in tile (MFMA col)
    const int g  = lane >> 4;   // k-group
    const int lt = wave;        // one l-tile per wave; wave 7 inactive
    const bool active = (lt < 7);
    const int l = lt * 16 + lr;

    // ---- Q B-frags from global (VMEM, no LDS dep) + register split ----
    short8b qh[2], ql[2];
    if (active) {
        const int lrow = (l < 100) ? l : 99;
        const float* qp = Q + ((size_t)(b * L_ + lrow) * H_ + h) * E_;
#pragma unroll
        for (int es = 0; es < 2; ++es) {
            float4 f0 = *(const float4*)(qp + es * 32 + g * 8);
            float4 f1 = *(const float4*)(qp + es * 32 + g * 8 + 4);
            float f[8] = {f0.x, f0.y, f0.z, f0.w, f1.x, f1.y, f1.z, f1.w};
            cvt_split8(f, qh[es], ql[es]);
        }
    }
    __syncthreads();

    if (active) {
        const float cs = 0.125f * LOG2E;
        float m1 = -INFINITY, m2 = -INFINITY, sum1 = 0.f, sum2 = 0.f, den = 0.f;
        uint2 pk[7];
#pragma unroll
        for (int jt = 0; jt < 7; ++jt) {
            int jrow = jt * 16 + lr; if (jrow > 99) jrow = 99;
            int rb = jrow * 128, sw = (jrow & 7) << 4;
            f32x4 C = {0.f, 0.f, 0.f, 0.f};
#pragma unroll
            for (int es = 0; es < 2; ++es) {
                int byte = (rb + g * 16 + es * 64) ^ sw;
                short8b kh = *(const short8b*)(smem + KHI + byte);
                short8b kl = *(const short8b*)(smem + KLO + byte);
                C = __builtin_amdgcn_mfma_f32_16x16x32_bf16(kh, qh[es], C, 0, 0, 0);
                C = __builtin_amdgcn_mfma_f32_16x16x32_bf16(kh, ql[es], C, 0, 0, 0);
                C = __builtin_amdgcn_mfma_f32_16x16x32_bf16(kl, qh[es], C, 0, 0, 0);
            }
            unsigned short pw[4] = {0, 0, 0, 0};
#pragma unroll
            for (int r = 0; r < 4; ++r) {
                int j = jt * 16 + g * 4 + r;
                float s = C[r];
                if (j < 100) {
                    m1 = fmaxf(m1, s);
                    sum1 += s;
                    bool band = (j - l < 3) && (l - j < 3);
                    float sp = band ? 0.f : s;
                    m2 = fmaxf(m2, sp);
                    sum2 += sp;
                    float p = exp2f(s * cs);
                    den += p;                           // diag included in den
                    pw[r] = (j == l) ? 0 : f2bf_rn(p);  // diag zeroed in output
                }
            }
            pk[jt].x = (unsigned)pw[0] | ((unsigned)pw[1] << 16);
            pk[jt].y = (unsigned)pw[2] | ((unsigned)pw[3] << 16);
        }
        // combine the 4 k-groups -> every lane holds full stats for its lr
        m1   = fmaxf(m1, __shfl_xor(m1, 16, 64));
        m1   = fmaxf(m1, __shfl_xor(m1, 32, 64));
        m2   = fmaxf(m2, __shfl_xor(m2, 16, 64));
        m2   = fmaxf(m2, __shfl_xor(m2, 32, 64));
        sum1 += __shfl_xor(sum1, 16, 64);
        sum1 += __shfl_xor(sum1, 32, 64);
        sum2 += __shfl_xor(sum2, 16, 64);
        sum2 += __shfl_xor(sum2, 32, 64);
        den  += __shfl_xor(den, 16, 64);
        den  += __shfl_xor(den, 32, 64);
        const float invd = 1.0f / den;

        if (lane < 16 && l < 100) {
            float M1 = m1 - sum1 * (1.0f / 100.0f);
            float M2 = m2 - sum2 * (1.0f / 94.0f);
            Mout[(size_t)bh * L_ + l] = M1 - M2;
        }
        if (l < 100) {
            float* srow = series + ((size_t)bh * L_ + l) * L_;
#pragma unroll
            for (int jt = 0; jt < 7; ++jt) {
                if (jt < 6 || g == 0) {
                    f32x4 p;
                    p.x = bf2f((unsigned short)(pk[jt].x & 0xFFFF)) * invd;
                    p.y = bf2f((unsigned short)(pk[jt].x >> 16))    * invd;
                    p.z = bf2f((unsigned short)(pk[jt].y & 0xFFFF)) * invd;
                    p.w = bf2f((unsigned short)(pk[jt].y >> 16))    * invd;
                    *(f32x4*)(srow + jt * 16 + g * 4) = p;   // L2-combined
                }
            }
        }

        // ---- PV: D[d][l] = sum_j V^T[d][j] P[l][j]; B-frags via shuffles --
        {
            f32x4 acc[4] = {{0.f,0.f,0.f,0.f},{0.f,0.f,0.f,0.f},
                            {0.f,0.f,0.f,0.f},{0.f,0.f,0.f,0.f}};
            const int src = lr + ((g & 1) << 5);
#pragma unroll
            for (int jt32 = 0; jt32 < 4; ++jt32) {
                uint2 sel;
                if (jt32 < 3) {
                    sel = (g & 2) ? pk[jt32 * 2 + 1] : pk[jt32 * 2];
                } else {  // pk[7] doesn't exist; those j>=112 are all zero
                    uint2 z; z.x = 0; z.y = 0;
                    sel = (g & 2) ? z : pk[6];
                }
                unsigned b0 = (unsigned)__shfl((int)sel.x, src, 64);
                unsigned b1 = (unsigned)__shfl((int)sel.y, src, 64);
                unsigned b2 = (unsigned)__shfl((int)sel.x, src + 16, 64);
                unsigned b3 = (unsigned)__shfl((int)sel.y, src + 16, 64);
                union { unsigned u[4]; short8b s; } bb;
                bb.u[0] = b0; bb.u[1] = b1; bb.u[2] = b2; bb.u[3] = b3;
                const int j0 = (jt32 == 3) ? 96 : (jt32 * 32 + g * 8);
#pragma unroll
                for (int dt = 0; dt < 4; ++dt) {
                    const char* ap = smem + VT + (dt * 16 + lr) * 240 + j0 * 2;
                    short8b Av = *(const short8b*)ap;
                    acc[dt] = __builtin_amdgcn_mfma_f32_16x16x32_bf16(Av, bb.s, acc[dt], 0, 0, 0);
                }
            }
            if (l < 100) {
#pragma unroll
                for (int dt = 0; dt < 4; ++dt) {
                    f32x4 o = acc[dt];
                    o.x *= invd; o.y *= invd; o.z *= invd; o.w *= invd;
                    *(f32x4*)(Vout + ((size_t)(b * L_ + l) * H_ + h) * D_ + dt * 16 + g * 4) = o;
                }
            }
        }
    }

    // ---- prior + sig tail: whole (b,h) tile, all 8 waves; LDS constants ----
    {
        const size_t base4 = (size_t)bh * 2500;
        const float4* d4 = (const float4*)dist;
        f32x4* p4 = (f32x4*)prior;
        f32x4* s4 = (f32x4*)sigout;
        for (int idx = t; idx < 2500; idx += 512) {
            int lrow = idx / 25;
            float sg = sgs[lrow], c1 = c1s[lrow], c2 = c2s[lrow];  // LDS broadcast
            float4 d = d4[idx];
            f32x4 pr;
            pr.x = c1 * exp2f(-d.x * d.x * c2);
            pr.y = c1 * exp2f(-d.y * d.y * c2);
            pr.z = c1 * exp2f(-d.z * d.z * c2);
            pr.w = c1 * exp2f(-d.w * d.w * c2);
            f32x4 sv = {sg, sg, sg, sg};
            __builtin_nontemporal_store(pr, p4 + base4 + idx);
            __builtin_nontemporal_store(sv, s4 + base4 + idx);
        }
    }
}

extern "C" void kernel_launch(void* const* d_in, const int* in_sizes, int n_in,
                              void* d_out, int out_size, void* d_ws, size_t ws_size,
                              hipStream_t stream) {
    const float* Q     = (const float*)d_in[0];
    const float* K     = (const float*)d_in[1];
    const float* V     = (const float*)d_in[2];
    const float* sigma = (const float*)d_in[3];
    const float* dist  = (const float*)d_in[4];

    float* out    = (float*)d_out;
    float* Vout   = out;
    float* series = out + OFF_SERIES;
    float* prior  = out + OFF_PRIOR;
    float* sigout = out + OFF_SIG;
    float* Mout   = out + OFF_M;

    hipLaunchKernelGGL(fused_kernel, dim3(B_ * H_), dim3(512), 0, stream,
                       Q, K, V, sigma, dist, Vout, series, prior, sigout, Mout);
}

// Round 15
// 97.166 us; speedup vs baseline: 4.0572x; 1.1093x over previous
//
#include <hip/hip_runtime.h>
#include <math.h>

#define B_ 256
#define L_ 100
#define H_ 8
#define E_ 64
#define D_ 64

// Output offsets (floats): V[B,L,H,D], series[B,H,L,L], prior, sig, M[B,H,L]
#define OFF_SERIES ((size_t)B_ * L_ * H_ * D_)
#define OFF_PRIOR  (OFF_SERIES + (size_t)B_ * H_ * L_ * L_)
#define OFF_SIG    (OFF_PRIOR  + (size_t)B_ * H_ * L_ * L_)
#define OFF_M      (OFF_SIG    + (size_t)B_ * H_ * L_ * L_)

#define LOG2E 1.4426950408889634f
#define LN3   1.0986122886681098f
#define INV_SQRT_2PI 0.3989422804014327f

typedef __attribute__((ext_vector_type(8))) short short8b;  // 8 bf16
typedef __attribute__((ext_vector_type(4))) float f32x4;

// LDS layout (bytes)
#define KHI 0        // K hi bf16 [100][64], 128B rows, XOR swizzle: 12800
#define KLO 12800    // K lo bf16: 12800
#define VT  25600    // V^T bf16 [64 d][120 j] (240B rows, 16B-aligned): 15360
#define SGC 40960    // sigma constants: sgs[100], c1s[100], c2s[100] f32
#define SMEM_BYTES 42240

__device__ __forceinline__ void cvt_split8(const float* f, short8b& hi, short8b& lo) {
#pragma unroll
    for (int i = 0; i < 8; ++i) {
        unsigned u = __float_as_uint(f[i]);
        hi[i] = (short)(u >> 16);
        float r = f[i] - __uint_as_float(u & 0xFFFF0000u);
        lo[i] = (short)(__float_as_uint(r) >> 16);
    }
}
__device__ __forceinline__ unsigned short f2bf_rn(float x) {  // round-to-nearest-even
    unsigned u = __float_as_uint(x);
    return (unsigned short)((u + 0x7FFFu + ((u >> 16) & 1u)) >> 16);
}
__device__ __forceinline__ float bf2f(unsigned short v) {
    return __uint_as_float((unsigned)v << 16);
}

// One 512-thread block per (b,h); K/V staged once; waves 0-6 one l-tile each.
// R15 vs R14: (1) co-resident blocks phase-staggered -- blocks with
// (bh>>8)&1 run the prior/sig tail BEFORE the attention compute so one
// block streams writes while its CU-partner computes; (2) dist computed
// on the fly in the tail (exact reference band semantics) -- no dist loads.
__global__ __launch_bounds__(512, 4) void fused_kernel(
    const float* __restrict__ Q, const float* __restrict__ K,
    const float* __restrict__ Vin, const float* __restrict__ sigma,
    const float* __restrict__ dist, float* __restrict__ Vout,
    float* __restrict__ series, float* __restrict__ prior,
    float* __restrict__ sigout, float* __restrict__ Mout) {
    const int bh = blockIdx.x;
    const int b = bh >> 3, h = bh & 7;
    const int stag = (bh >> 8) & 1;   // co-resident partner has opposite bit
    __shared__ __align__(16) char smem[SMEM_BYTES];
    float* sgs = (float*)(smem + SGC);
    float* c1s = sgs + 100;
    float* c2s = sgs + 200;
    const int t = threadIdx.x;

    // ---- stage K as split-bf16 hi/lo (row XOR-swizzle, R4-proven) ----
    for (int ci = t; ci < 800; ci += 512) {
        int row = ci >> 3, c8 = ci & 7;
        const float* src = K + ((size_t)(b * L_ + row) * H_ + h) * E_ + c8 * 8;
        float4 f0 = *(const float4*)src;
        float4 f1 = *(const float4*)(src + 4);
        float f[8] = {f0.x, f0.y, f0.z, f0.w, f1.x, f1.y, f1.z, f1.w};
        short8b hi8, lo8;
        cvt_split8(f, hi8, lo8);
        int byte = (row * 128 + c8 * 16) ^ ((row & 7) << 4);
        *(short8b*)(smem + KHI + byte) = hi8;
        *(short8b*)(smem + KLO + byte) = lo8;
    }
    // ---- stage V^T bf16 [64][120], two j-columns per u32 write ----
    for (int f = t; f < 800; f += 512) {
        int j2 = f >> 4, c = f & 15;   // j2: 0..49, c: 0..15
        const float* vp = Vin + ((size_t)(b * L_ + 2 * j2) * H_ + h) * D_ + c * 4;
        float4 v0 = *(const float4*)vp;
        float4 v1 = *(const float4*)(vp + H_ * D_);
        float a0[4] = {v0.x, v0.y, v0.z, v0.w};
        float a1[4] = {v1.x, v1.y, v1.z, v1.w};
#pragma unroll
        for (int i = 0; i < 4; ++i) {
            unsigned pkd = (unsigned)f2bf_rn(a0[i]) | ((unsigned)f2bf_rn(a1[i]) << 16);
            *(unsigned*)(smem + VT + (c * 4 + i) * 240 + j2 * 4) = pkd;
        }
    }
    if (t < 64) {   // zero cols 100..105 (k-tail reads cover <=103)
        *(unsigned*)(smem + VT + t * 240 + 200) = 0;
        *(unsigned*)(smem + VT + t * 240 + 204) = 0;
        *(unsigned*)(smem + VT + t * 240 + 208) = 0;
    }
    if (t < 100) {  // sigma-derived per-row constants, once per block
        float x = sigma[((size_t)b * L_ + t) * H_ + h];
        float s = 1.0f / (1.0f + exp2f(-5.0f * LOG2E * x)) + 1e-5f;
        float sg = expm1f(s * LN3);   // 3^s - 1, accurate near 0
        float inv = 1.0f / sg;
        sgs[t] = sg;
        c1s[t] = INV_SQRT_2PI * inv;
        c2s[t] = 0.5f * LOG2E * inv * inv;
    }

    const int wave = t >> 6;
    const int lane = t & 63;
    const int lr = lane & 15;   // l-offset in tile (MFMA col)
    const int g  = lane >> 4;   // k-group
    const int lt = wave;        // one l-tile per wave; wave 7 inactive
    const bool active = (lt < 7);
    const int l = lt * 16 + lr;

    // ---- Q B-frags from global (VMEM, no LDS dep) + register split ----
    short8b qh[2], ql[2];
    if (active) {
        const int lrow = (l < 100) ? l : 99;
        const float* qp = Q + ((size_t)(b * L_ + lrow) * H_ + h) * E_;
#pragma unroll
        for (int es = 0; es < 2; ++es) {
            float4 f0 = *(const float4*)(qp + es * 32 + g * 8);
            float4 f1 = *(const float4*)(qp + es * 32 + g * 8 + 4);
            float f[8] = {f0.x, f0.y, f0.z, f0.w, f1.x, f1.y, f1.z, f1.w};
            cvt_split8(f, qh[es], ql[es]);
        }
    }
    __syncthreads();

    // ================= prior + sig tail (as a lambda-ish macro) ==========
    // dist on the fly: d=|i-j|, zeroed per the reference band conditions:
    // upper: j>=i && j<i+3 && i<=96 ; lower: j<=i && j>i-3 && i>=3
#define PRIOR_TAIL()                                                        \
    {                                                                       \
        const size_t base4 = (size_t)bh * 2500;                             \
        f32x4* p4 = (f32x4*)prior;                                          \
        f32x4* s4 = (f32x4*)sigout;                                         \
        for (int idx = t; idx < 2500; idx += 512) {                         \
            int lrow = idx / 25;                                            \
            int j0 = (idx - lrow * 25) * 4;                                 \
            float sg = sgs[lrow], c1 = c1s[lrow], c2 = c2s[lrow];           \
            f32x4 pr;                                                       \
            float* prp = (float*)&pr;                                       \
            _Pragma("unroll")                                               \
            for (int k = 0; k < 4; ++k) {                                   \
                int j = j0 + k;                                             \
                bool z = (j >= lrow && j - lrow < 3 && lrow <= 96) ||       \
                         (j <= lrow && lrow - j < 3 && lrow >= 3);          \
                float d = z ? 0.f : fabsf((float)(lrow - j));               \
                prp[k] = c1 * exp2f(-d * d * c2);                           \
            }                                                               \
            f32x4 sv = {sg, sg, sg, sg};                                    \
            __builtin_nontemporal_store(pr, p4 + base4 + idx);              \
            __builtin_nontemporal_store(sv, s4 + base4 + idx);              \
        }                                                                   \
    }

    if (stag) PRIOR_TAIL();   // second co-resident block: write burst first

    if (active) {
        const float cs = 0.125f * LOG2E;
        float m1 = -INFINITY, m2 = -INFINITY, sum1 = 0.f, sum2 = 0.f, den = 0.f;
        uint2 pk[7];
#pragma unroll
        for (int jt = 0; jt < 7; ++jt) {
            int jrow = jt * 16 + lr; if (jrow > 99) jrow = 99;
            int rb = jrow * 128, sw = (jrow & 7) << 4;
            f32x4 C = {0.f, 0.f, 0.f, 0.f};
#pragma unroll
            for (int es = 0; es < 2; ++es) {
                int byte = (rb + g * 16 + es * 64) ^ sw;
                short8b kh = *(const short8b*)(smem + KHI + byte);
                short8b kl = *(const short8b*)(smem + KLO + byte);
                C = __builtin_amdgcn_mfma_f32_16x16x32_bf16(kh, qh[es], C, 0, 0, 0);
                C = __builtin_amdgcn_mfma_f32_16x16x32_bf16(kh, ql[es], C, 0, 0, 0);
                C = __builtin_amdgcn_mfma_f32_16x16x32_bf16(kl, qh[es], C, 0, 0, 0);
            }
            unsigned short pw[4] = {0, 0, 0, 0};
#pragma unroll
            for (int r = 0; r < 4; ++r) {
                int j = jt * 16 + g * 4 + r;
                float s = C[r];
                if (j < 100) {
                    m1 = fmaxf(m1, s);
                    sum1 += s;
                    bool band = (j - l < 3) && (l - j < 3);
                    float sp = band ? 0.f : s;
                    m2 = fmaxf(m2, sp);
                    sum2 += sp;
                    float p = exp2f(s * cs);
                    den += p;                           // diag included in den
                    pw[r] = (j == l) ? 0 : f2bf_rn(p);  // diag zeroed in output
                }
            }
            pk[jt].x = (unsigned)pw[0] | ((unsigned)pw[1] << 16);
            pk[jt].y = (unsigned)pw[2] | ((unsigned)pw[3] << 16);
        }
        // combine the 4 k-groups -> every lane holds full stats for its lr
        m1   = fmaxf(m1, __shfl_xor(m1, 16, 64));
        m1   = fmaxf(m1, __shfl_xor(m1, 32, 64));
        m2   = fmaxf(m2, __shfl_xor(m2, 16, 64));
        m2   = fmaxf(m2, __shfl_xor(m2, 32, 64));
        sum1 += __shfl_xor(sum1, 16, 64);
        sum1 += __shfl_xor(sum1, 32, 64);
        sum2 += __shfl_xor(sum2, 16, 64);
        sum2 += __shfl_xor(sum2, 32, 64);
        den  += __shfl_xor(den, 16, 64);
        den  += __shfl_xor(den, 32, 64);
        const float invd = 1.0f / den;

        if (lane < 16 && l < 100) {
            float M1 = m1 - sum1 * (1.0f / 100.0f);
            float M2 = m2 - sum2 * (1.0f / 94.0f);
            Mout[(size_t)bh * L_ + l] = M1 - M2;
        }
        if (l < 100) {
            float* srow = series + ((size_t)bh * L_ + l) * L_;
#pragma unroll
            for (int jt = 0; jt < 7; ++jt) {
                if (jt < 6 || g == 0) {
                    f32x4 p;
                    p.x = bf2f((unsigned short)(pk[jt].x & 0xFFFF)) * invd;
                    p.y = bf2f((unsigned short)(pk[jt].x >> 16))    * invd;
                    p.z = bf2f((unsigned short)(pk[jt].y & 0xFFFF)) * invd;
                    p.w = bf2f((unsigned short)(pk[jt].y >> 16))    * invd;
                    *(f32x4*)(srow + jt * 16 + g * 4) = p;   // L2-combined
                }
            }
        }

        // ---- PV: D[d][l] = sum_j V^T[d][j] P[l][j]; B-frags via shuffles --
        {
            f32x4 acc[4] = {{0.f,0.f,0.f,0.f},{0.f,0.f,0.f,0.f},
                            {0.f,0.f,0.f,0.f},{0.f,0.f,0.f,0.f}};
            const int src = lr + ((g & 1) << 5);
#pragma unroll
            for (int jt32 = 0; jt32 < 4; ++jt32) {
                uint2 sel;
                if (jt32 < 3) {
                    sel = (g & 2) ? pk[jt32 * 2 + 1] : pk[jt32 * 2];
                } else {  // pk[7] doesn't exist; those j>=112 are all zero
                    uint2 z; z.x = 0; z.y = 0;
                    sel = (g & 2) ? z : pk[6];
                }
                unsigned b0 = (unsigned)__shfl((int)sel.x, src, 64);
                unsigned b1 = (unsigned)__shfl((int)sel.y, src, 64);
                unsigned b2 = (unsigned)__shfl((int)sel.x, src + 16, 64);
                unsigned b3 = (unsigned)__shfl((int)sel.y, src + 16, 64);
                union { unsigned u[4]; short8b s; } bb;
                bb.u[0] = b0; bb.u[1] = b1; bb.u[2] = b2; bb.u[3] = b3;
                const int j0 = (jt32 == 3) ? 96 : (jt32 * 32 + g * 8);
#pragma unroll
                for (int dt = 0; dt < 4; ++dt) {
                    const char* ap = smem + VT + (dt * 16 + lr) * 240 + j0 * 2;
                    short8b Av = *(const short8b*)ap;
                    acc[dt] = __builtin_amdgcn_mfma_f32_16x16x32_bf16(Av, bb.s, acc[dt], 0, 0, 0);
                }
            }
            if (l < 100) {
#pragma unroll
                for (int dt = 0; dt < 4; ++dt) {
                    f32x4 o = acc[dt];
                    o.x *= invd; o.y *= invd; o.z *= invd; o.w *= invd;
                    *(f32x4*)(Vout + ((size_t)(b * L_ + l) * H_ + h) * D_ + dt * 16 + g * 4) = o;
                }
            }
        }
    }

    if (!stag) PRIOR_TAIL();   // first co-resident block: write burst last
}

extern "C" void kernel_launch(void* const* d_in, const int* in_sizes, int n_in,
                              void* d_out, int out_size, void* d_ws, size_t ws_size,
                              hipStream_t stream) {
    const float* Q     = (const float*)d_in[0];
    const float* K     = (const float*)d_in[1];
    const float* V     = (const float*)d_in[2];
    const float* sigma = (const float*)d_in[3];
    const float* dist  = (const float*)d_in[4];

    float* out    = (float*)d_out;
    float* Vout   = out;
    float* series = out + OFF_SERIES;
    float* prior  = out + OFF_PRIOR;
    float* sigout = out + OFF_SIG;
    float* Mout   = out + OFF_M;

    hipLaunchKernelGGL(fused_kernel, dim3(B_ * H_), dim3(512), 0, stream,
                       Q, K, V, sigma, dist, Vout, series, prior, sigout, Mout);
}

// Round 16
// 96.630 us; speedup vs baseline: 4.0797x; 1.0055x over previous
//
#include <hip/hip_runtime.h>
#include <math.h>

#define B_ 256
#define L_ 100
#define H_ 8
#define E_ 64
#define D_ 64

// Output offsets (floats): V[B,L,H,D], series[B,H,L,L], prior, sig, M[B,H,L]
#define OFF_SERIES ((size_t)B_ * L_ * H_ * D_)
#define OFF_PRIOR  (OFF_SERIES + (size_t)B_ * H_ * L_ * L_)
#define OFF_SIG    (OFF_PRIOR  + (size_t)B_ * H_ * L_ * L_)
#define OFF_M      (OFF_SIG    + (size_t)B_ * H_ * L_ * L_)

#define LOG2E 1.4426950408889634f
#define LN3   1.0986122886681098f
#define INV_SQRT_2PI 0.3989422804014327f

typedef __attribute__((ext_vector_type(8))) short short8b;  // 8 bf16
typedef __attribute__((ext_vector_type(4))) float f32x4;

// LDS layout (bytes)
#define KHI 0        // K hi bf16 [100][64], 128B rows, XOR swizzle: 12800
#define KLO 12800    // K lo bf16: 12800
#define VT  25600    // V^T bf16 [64 d][120 j] (240B rows, 16B-aligned): 15360
#define SGC 40960    // sigma constants: sgs[100], c1s[100], c2s[100] f32
#define SMEM_BYTES 42240

__device__ __forceinline__ void cvt_split8(const float* f, short8b& hi, short8b& lo) {
#pragma unroll
    for (int i = 0; i < 8; ++i) {
        unsigned u = __float_as_uint(f[i]);
        hi[i] = (short)(u >> 16);
        float r = f[i] - __uint_as_float(u & 0xFFFF0000u);
        lo[i] = (short)(__float_as_uint(r) >> 16);
    }
}
__device__ __forceinline__ unsigned short f2bf_rn(float x) {  // round-to-nearest-even
    unsigned u = __float_as_uint(x);
    return (unsigned short)((u + 0x7FFFu + ((u >> 16) & 1u)) >> 16);
}
__device__ __forceinline__ float bf2f(unsigned short v) {
    return __uint_as_float((unsigned)v << 16);
}

// One 512-thread block per (b,h); K/V staged once; waves 0-6 one l-tile each.
// R16 vs R15: (1) s_setprio(1) around the QK^T and PV MFMA clusters (waves
// here are phase-diverse: stage/tail/compute co-resident -> T5 applies);
// (2) tail d^2 as integer product (fewer VALU on the 164MB write path).
__global__ __launch_bounds__(512, 4) void fused_kernel(
    const float* __restrict__ Q, const float* __restrict__ K,
    const float* __restrict__ Vin, const float* __restrict__ sigma,
    const float* __restrict__ dist, float* __restrict__ Vout,
    float* __restrict__ series, float* __restrict__ prior,
    float* __restrict__ sigout, float* __restrict__ Mout) {
    const int bh = blockIdx.x;
    const int b = bh >> 3, h = bh & 7;
    const int stag = (bh >> 8) & 1;   // co-resident partner has opposite bit
    __shared__ __align__(16) char smem[SMEM_BYTES];
    float* sgs = (float*)(smem + SGC);
    float* c1s = sgs + 100;
    float* c2s = sgs + 200;
    const int t = threadIdx.x;

    // ---- stage K as split-bf16 hi/lo (row XOR-swizzle, R4-proven) ----
    for (int ci = t; ci < 800; ci += 512) {
        int row = ci >> 3, c8 = ci & 7;
        const float* src = K + ((size_t)(b * L_ + row) * H_ + h) * E_ + c8 * 8;
        float4 f0 = *(const float4*)src;
        float4 f1 = *(const float4*)(src + 4);
        float f[8] = {f0.x, f0.y, f0.z, f0.w, f1.x, f1.y, f1.z, f1.w};
        short8b hi8, lo8;
        cvt_split8(f, hi8, lo8);
        int byte = (row * 128 + c8 * 16) ^ ((row & 7) << 4);
        *(short8b*)(smem + KHI + byte) = hi8;
        *(short8b*)(smem + KLO + byte) = lo8;
    }
    // ---- stage V^T bf16 [64][120], two j-columns per u32 write ----
    for (int f = t; f < 800; f += 512) {
        int j2 = f >> 4, c = f & 15;   // j2: 0..49, c: 0..15
        const float* vp = Vin + ((size_t)(b * L_ + 2 * j2) * H_ + h) * D_ + c * 4;
        float4 v0 = *(const float4*)vp;
        float4 v1 = *(const float4*)(vp + H_ * D_);
        float a0[4] = {v0.x, v0.y, v0.z, v0.w};
        float a1[4] = {v1.x, v1.y, v1.z, v1.w};
#pragma unroll
        for (int i = 0; i < 4; ++i) {
            unsigned pkd = (unsigned)f2bf_rn(a0[i]) | ((unsigned)f2bf_rn(a1[i]) << 16);
            *(unsigned*)(smem + VT + (c * 4 + i) * 240 + j2 * 4) = pkd;
        }
    }
    if (t < 64) {   // zero cols 100..105 (k-tail reads cover <=103)
        *(unsigned*)(smem + VT + t * 240 + 200) = 0;
        *(unsigned*)(smem + VT + t * 240 + 204) = 0;
        *(unsigned*)(smem + VT + t * 240 + 208) = 0;
    }
    if (t < 100) {  // sigma-derived per-row constants, once per block
        float x = sigma[((size_t)b * L_ + t) * H_ + h];
        float s = 1.0f / (1.0f + exp2f(-5.0f * LOG2E * x)) + 1e-5f;
        float sg = expm1f(s * LN3);   // 3^s - 1, accurate near 0
        float inv = 1.0f / sg;
        sgs[t] = sg;
        c1s[t] = INV_SQRT_2PI * inv;
        c2s[t] = 0.5f * LOG2E * inv * inv;
    }

    const int wave = t >> 6;
    const int lane = t & 63;
    const int lr = lane & 15;   // l-offset in tile (MFMA col)
    const int g  = lane >> 4;   // k-group
    const int lt = wave;        // one l-tile per wave; wave 7 inactive
    const bool active = (lt < 7);
    const int l = lt * 16 + lr;

    // ---- Q B-frags from global (VMEM, no LDS dep) + register split ----
    short8b qh[2], ql[2];
    if (active) {
        const int lrow = (l < 100) ? l : 99;
        const float* qp = Q + ((size_t)(b * L_ + lrow) * H_ + h) * E_;
#pragma unroll
        for (int es = 0; es < 2; ++es) {
            float4 f0 = *(const float4*)(qp + es * 32 + g * 8);
            float4 f1 = *(const float4*)(qp + es * 32 + g * 8 + 4);
            float f[8] = {f0.x, f0.y, f0.z, f0.w, f1.x, f1.y, f1.z, f1.w};
            cvt_split8(f, qh[es], ql[es]);
        }
    }
    __syncthreads();

    // ================= prior + sig tail =================
    // dist on the fly: d=|i-j|, zeroed per the reference band conditions:
    // upper: j>=i && j<i+3 && i<=96 ; lower: j<=i && j>i-3 && i>=3
#define PRIOR_TAIL()                                                        \
    {                                                                       \
        const size_t base4 = (size_t)bh * 2500;                             \
        f32x4* p4 = (f32x4*)prior;                                          \
        f32x4* s4 = (f32x4*)sigout;                                         \
        for (int idx = t; idx < 2500; idx += 512) {                         \
            int lrow = idx / 25;                                            \
            int j0 = (idx - lrow * 25) * 4;                                 \
            float sg = sgs[lrow], c1 = c1s[lrow], c2 = c2s[lrow];           \
            f32x4 pr;                                                       \
            float* prp = (float*)&pr;                                       \
            _Pragma("unroll")                                               \
            for (int k = 0; k < 4; ++k) {                                   \
                int j = j0 + k;                                             \
                bool z = (j >= lrow && j - lrow < 3 && lrow <= 96) ||       \
                         (j <= lrow && lrow - j < 3 && lrow >= 3);          \
                int di = lrow - j;                                          \
                int d2 = z ? 0 : di * di;                                   \
                prp[k] = c1 * exp2f(-(float)d2 * c2);                       \
            }                                                               \
            f32x4 sv = {sg, sg, sg, sg};                                    \
            __builtin_nontemporal_store(pr, p4 + base4 + idx);              \
            __builtin_nontemporal_store(sv, s4 + base4 + idx);              \
        }                                                                   \
    }

    if (stag) PRIOR_TAIL();   // second co-resident block: write burst first

    if (active) {
        const float cs = 0.125f * LOG2E;
        float m1 = -INFINITY, m2 = -INFINITY, sum1 = 0.f, sum2 = 0.f, den = 0.f;
        uint2 pk[7];
#pragma unroll
        for (int jt = 0; jt < 7; ++jt) {
            int jrow = jt * 16 + lr; if (jrow > 99) jrow = 99;
            int rb = jrow * 128, sw = (jrow & 7) << 4;
            f32x4 C = {0.f, 0.f, 0.f, 0.f};
            __builtin_amdgcn_s_setprio(1);
#pragma unroll
            for (int es = 0; es < 2; ++es) {
                int byte = (rb + g * 16 + es * 64) ^ sw;
                short8b kh = *(const short8b*)(smem + KHI + byte);
                short8b kl = *(const short8b*)(smem + KLO + byte);
                C = __builtin_amdgcn_mfma_f32_16x16x32_bf16(kh, qh[es], C, 0, 0, 0);
                C = __builtin_amdgcn_mfma_f32_16x16x32_bf16(kh, ql[es], C, 0, 0, 0);
                C = __builtin_amdgcn_mfma_f32_16x16x32_bf16(kl, qh[es], C, 0, 0, 0);
            }
            __builtin_amdgcn_s_setprio(0);
            unsigned short pw[4] = {0, 0, 0, 0};
#pragma unroll
            for (int r = 0; r < 4; ++r) {
                int j = jt * 16 + g * 4 + r;
                float s = C[r];
                if (j < 100) {
                    m1 = fmaxf(m1, s);
                    sum1 += s;
                    bool band = (j - l < 3) && (l - j < 3);
                    float sp = band ? 0.f : s;
                    m2 = fmaxf(m2, sp);
                    sum2 += sp;
                    float p = exp2f(s * cs);
                    den += p;                           // diag included in den
                    pw[r] = (j == l) ? 0 : f2bf_rn(p);  // diag zeroed in output
                }
            }
            pk[jt].x = (unsigned)pw[0] | ((unsigned)pw[1] << 16);
            pk[jt].y = (unsigned)pw[2] | ((unsigned)pw[3] << 16);
        }
        // combine the 4 k-groups -> every lane holds full stats for its lr
        m1   = fmaxf(m1, __shfl_xor(m1, 16, 64));
        m1   = fmaxf(m1, __shfl_xor(m1, 32, 64));
        m2   = fmaxf(m2, __shfl_xor(m2, 16, 64));
        m2   = fmaxf(m2, __shfl_xor(m2, 32, 64));
        sum1 += __shfl_xor(sum1, 16, 64);
        sum1 += __shfl_xor(sum1, 32, 64);
        sum2 += __shfl_xor(sum2, 16, 64);
        sum2 += __shfl_xor(sum2, 32, 64);
        den  += __shfl_xor(den, 16, 64);
        den  += __shfl_xor(den, 32, 64);
        const float invd = 1.0f / den;

        if (lane < 16 && l < 100) {
            float M1 = m1 - sum1 * (1.0f / 100.0f);
            float M2 = m2 - sum2 * (1.0f / 94.0f);
            Mout[(size_t)bh * L_ + l] = M1 - M2;
        }
        if (l < 100) {
            float* srow = series + ((size_t)bh * L_ + l) * L_;
#pragma unroll
            for (int jt = 0; jt < 7; ++jt) {
                if (jt < 6 || g == 0) {
                    f32x4 p;
                    p.x = bf2f((unsigned short)(pk[jt].x & 0xFFFF)) * invd;
                    p.y = bf2f((unsigned short)(pk[jt].x >> 16))    * invd;
                    p.z = bf2f((unsigned short)(pk[jt].y & 0xFFFF)) * invd;
                    p.w = bf2f((unsigned short)(pk[jt].y >> 16))    * invd;
                    *(f32x4*)(srow + jt * 16 + g * 4) = p;   // L2-combined
                }
            }
        }

        // ---- PV: D[d][l] = sum_j V^T[d][j] P[l][j]; B-frags via shuffles --
        {
            f32x4 acc[4] = {{0.f,0.f,0.f,0.f},{0.f,0.f,0.f,0.f},
                            {0.f,0.f,0.f,0.f},{0.f,0.f,0.f,0.f}};
            const int src = lr + ((g & 1) << 5);
#pragma unroll
            for (int jt32 = 0; jt32 < 4; ++jt32) {
                uint2 sel;
                if (jt32 < 3) {
                    sel = (g & 2) ? pk[jt32 * 2 + 1] : pk[jt32 * 2];
                } else {  // pk[7] doesn't exist; those j>=112 are all zero
                    uint2 z; z.x = 0; z.y = 0;
                    sel = (g & 2) ? z : pk[6];
                }
                unsigned b0 = (unsigned)__shfl((int)sel.x, src, 64);
                unsigned b1 = (unsigned)__shfl((int)sel.y, src, 64);
                unsigned b2 = (unsigned)__shfl((int)sel.x, src + 16, 64);
                unsigned b3 = (unsigned)__shfl((int)sel.y, src + 16, 64);
                union { unsigned u[4]; short8b s; } bb;
                bb.u[0] = b0; bb.u[1] = b1; bb.u[2] = b2; bb.u[3] = b3;
                const int j0 = (jt32 == 3) ? 96 : (jt32 * 32 + g * 8);
                __builtin_amdgcn_s_setprio(1);
#pragma unroll
                for (int dt = 0; dt < 4; ++dt) {
                    const char* ap = smem + VT + (dt * 16 + lr) * 240 + j0 * 2;
                    short8b Av = *(const short8b*)ap;
                    acc[dt] = __builtin_amdgcn_mfma_f32_16x16x32_bf16(Av, bb.s, acc[dt], 0, 0, 0);
                }
                __builtin_amdgcn_s_setprio(0);
            }
            if (l < 100) {
#pragma unroll
                for (int dt = 0; dt < 4; ++dt) {
                    f32x4 o = acc[dt];
                    o.x *= invd; o.y *= invd; o.z *= invd; o.w *= invd;
                    *(f32x4*)(Vout + ((size_t)(b * L_ + l) * H_ + h) * D_ + dt * 16 + g * 4) = o;
                }
            }
        }
    }

    if (!stag) PRIOR_TAIL();   // first co-resident block: write burst last
}

extern "C" void kernel_launch(void* const* d_in, const int* in_sizes, int n_in,
                              void* d_out, int out_size, void* d_ws, size_t ws_size,
                              hipStream_t stream) {
    const float* Q     = (const float*)d_in[0];
    const float* K     = (const float*)d_in[1];
    const float* V     = (const float*)d_in[2];
    const float* sigma = (const float*)d_in[3];
    const float* dist  = (const float*)d_in[4];

    float* out    = (float*)d_out;
    float* Vout   = out;
    float* series = out + OFF_SERIES;
    float* prior  = out + OFF_PRIOR;
    float* sigout = out + OFF_SIG;
    float* Mout   = out + OFF_M;

    hipLaunchKernelGGL(fused_kernel, dim3(B_ * H_), dim3(512), 0, stream,
                       Q, K, V, sigma, dist, Vout, series, prior, sigout, Mout);
}